// Round 14
// baseline (217.576 us; speedup 1.0000x reference)
//
#include <hip/hip_runtime.h>
#include <cstdint>
#include <math.h>

static constexpr int Bc = 2, Tc = 2048, Cch = 512, Hc = 8;
static constexpr int BT = Bc * Tc;          // 4096
static constexpr int NBH = Bc * Hc;         // 16
static constexpr int NRT = Tc / 128;        // 16 row-tiles per (b,h)
static constexpr int NTRI = NRT * (NRT + 1) / 2;  // 136 causal blocks
static constexpr size_t TRI_FLOATS = (size_t)NTRI * 16384;  // f32 per (b,h)

typedef float f32x4 __attribute__((ext_vector_type(4)));
typedef short s16x8 __attribute__((ext_vector_type(8)));
typedef unsigned short u16x8 __attribute__((ext_vector_type(8)));
typedef unsigned short u16x4 __attribute__((ext_vector_type(4)));

__device__ __host__ inline constexpr int tri_i(int r) { return r * (r + 1) / 2; }

__device__ inline float wave_sum_f(float x) {
#pragma unroll
  for (int o = 32; o; o >>= 1) x += __shfl_xor(x, o);
  return x;
}
__device__ inline unsigned short f2bf(float x) {  // RNE f32->bf16 (finite)
  unsigned u = __float_as_uint(x);
  return (unsigned short)((u + 0x7FFFu + ((u >> 16) & 1u)) >> 16);
}
__device__ inline float bf2f(unsigned short h) { return __uint_as_float(((unsigned)h) << 16); }
__device__ inline float su2f(unsigned s) {  // inverse order-preserving map
  unsigned u = (s & 0x80000000u) ? (s ^ 0x80000000u) : ~s;
  return __uint_as_float(u);
}

// ---------- split + transpose all 4 weights: W[k][n] f32 -> WT[n][k] bf16 hi/lo ----------
__global__ __launch_bounds__(256) void splitT4_k(const float* __restrict__ Wq,
    const float* __restrict__ Wk, const float* __restrict__ Wv,
    const float* __restrict__ Wp, unsigned short* __restrict__ wsp) {
  const int z = blockIdx.z;
  const float* W = (z == 0) ? Wq : (z == 1) ? Wk : (z == 2) ? Wv : Wp;
  unsigned short* hiT = wsp + (size_t)z * 524288;
  unsigned short* loT = hiT + 262144;
  __shared__ float t[64][65];
  const int tid = threadIdx.x;
  const int k0 = blockIdx.x * 64, n0 = blockIdx.y * 64;
#pragma unroll
  for (int p = 0; p < 4; p++) {
    int idx = tid + p * 256, kk = idx >> 4, n4 = idx & 15;
    f32x4 v = *(const f32x4*)&W[(size_t)(k0 + kk) * Cch + n0 + n4 * 4];
    t[kk][n4 * 4 + 0] = v[0]; t[kk][n4 * 4 + 1] = v[1];
    t[kk][n4 * 4 + 2] = v[2]; t[kk][n4 * 4 + 3] = v[3];
  }
  __syncthreads();
  {
    int n = tid >> 2, ks = tid & 3;
    u16x8 h0, h1, l0, l1;
#pragma unroll
    for (int kk = 0; kk < 8; kk++) {
      float x = t[ks * 16 + kk][n];
      unsigned short hh = f2bf(x);
      h0[kk] = hh; l0[kk] = f2bf(x - bf2f(hh));
      float y = t[ks * 16 + 8 + kk][n];
      unsigned short hy = f2bf(y);
      h1[kk] = hy; l1[kk] = f2bf(y - bf2f(hy));
    }
    size_t base = (size_t)(n0 + n) * Cch + k0 + ks * 16;
    *(u16x8*)(hiT + base) = h0; *(u16x8*)(hiT + base + 8) = h1;
    *(u16x8*)(loT + base) = l0; *(u16x8*)(loT + base + 8) = l1;
  }
}

// ---------- merged Q/K/V projection: reads q f32, splits hi/lo inline while staging ----------
__global__ __launch_bounds__(512) void gemm3w_qkv_k(
    const float* __restrict__ Aq, const unsigned short* __restrict__ wsp,
    const float* __restrict__ bq, const float* __restrict__ bk, const float* __restrict__ bv,
    unsigned short* __restrict__ Qp, unsigned short* __restrict__ Kp, float* __restrict__ Vf) {
  const int z = blockIdx.z;
  const unsigned short* Bhi = wsp + (size_t)z * 524288;
  const unsigned short* Blo = Bhi + 262144;
  const float* bias = (z == 0) ? bq : (z == 1) ? bk : bv;
  __shared__ unsigned short Ah[2][128][72];
  __shared__ unsigned short Bs[2][64][72];
  const int tid = threadIdx.x;
  const int w = tid >> 6, lane = tid & 63, e = lane >> 4, lr = lane & 15;
  const int wr = w >> 1, wc = w & 1;                 // 4x2 wave grid
  const int brow = blockIdx.y * 128, bcol = blockIdx.x * 64;
  f32x4 acc[2][2] = {};
  for (int k0 = 0; k0 < Cch; k0 += 64) {
#pragma unroll
    for (int p = 0; p < 4; p++) {
      int idx = tid + p * 512, row = idx >> 4, seg = idx & 15;  // 128 rows x 16 f32x4 segs
      f32x4 v = *(const f32x4*)&Aq[(size_t)(brow + row) * Cch + k0 + seg * 4];
      u16x4 hv, lv;
#pragma unroll
      for (int c = 0; c < 4; c++) {
        unsigned short hh = f2bf(v[c]);
        hv[c] = hh;
        lv[c] = f2bf(v[c] - bf2f(hh));
      }
      *(u16x4*)&Ah[0][row][seg * 4] = hv;
      *(u16x4*)&Ah[1][row][seg * 4] = lv;
    }
    {
      int row = tid >> 3, seg = tid & 7;
      *(u16x8*)&Bs[0][row][seg * 8] = *(const u16x8*)&Bhi[(size_t)(bcol + row) * Cch + k0 + seg * 8];
      *(u16x8*)&Bs[1][row][seg * 8] = *(const u16x8*)&Blo[(size_t)(bcol + row) * Cch + k0 + seg * 8];
    }
    __syncthreads();
#pragma unroll
    for (int ks = 0; ks < 2; ks++) {
      s16x8 ah[2], al[2], bh[2], bl[2];
#pragma unroll
      for (int ti = 0; ti < 2; ti++) {
        ah[ti] = *(const s16x8*)&Ah[0][wr * 32 + ti * 16 + lr][ks * 32 + e * 8];
        al[ti] = *(const s16x8*)&Ah[1][wr * 32 + ti * 16 + lr][ks * 32 + e * 8];
      }
#pragma unroll
      for (int tj = 0; tj < 2; tj++) {
        bh[tj] = *(const s16x8*)&Bs[0][wc * 32 + tj * 16 + lr][ks * 32 + e * 8];
        bl[tj] = *(const s16x8*)&Bs[1][wc * 32 + tj * 16 + lr][ks * 32 + e * 8];
      }
#pragma unroll
      for (int ti = 0; ti < 2; ti++)
#pragma unroll
        for (int tj = 0; tj < 2; tj++) {
          acc[ti][tj] = __builtin_amdgcn_mfma_f32_16x16x32_bf16(ah[ti], bh[tj], acc[ti][tj], 0, 0, 0);
          acc[ti][tj] = __builtin_amdgcn_mfma_f32_16x16x32_bf16(ah[ti], bl[tj], acc[ti][tj], 0, 0, 0);
          acc[ti][tj] = __builtin_amdgcn_mfma_f32_16x16x32_bf16(al[ti], bh[tj], acc[ti][tj], 0, 0, 0);
        }
    }
    __syncthreads();
  }
#pragma unroll
  for (int ti = 0; ti < 2; ti++)
#pragma unroll
    for (int tj = 0; tj < 2; tj++) {
      int col = bcol + wc * 32 + tj * 16 + lr;
      float bi = bias[col];
#pragma unroll
      for (int r = 0; r < 4; r++) {
        int row = brow + wr * 32 + ti * 16 + e * 4 + r;
        float v = acc[ti][tj][r] + bi;
        size_t g = (size_t)row * Cch + col;
        if (z == 0) Qp[g] = f2bf(v);
        else if (z == 1) Kp[g] = f2bf(v);
        else Vf[g] = v;
      }
    }
}

// ---------- output projection: A pre-split (Yhi/Ylo), f32 out ----------
__global__ __launch_bounds__(512) void gemm3w_out_k(
    const unsigned short* __restrict__ Ahi, const unsigned short* __restrict__ Alo,
    const unsigned short* __restrict__ Bhi, const unsigned short* __restrict__ Blo,
    const float* __restrict__ bias, float* __restrict__ Out) {
  __shared__ unsigned short Ah[2][128][72];
  __shared__ unsigned short Bs[2][64][72];
  const int tid = threadIdx.x;
  const int w = tid >> 6, lane = tid & 63, e = lane >> 4, lr = lane & 15;
  const int wr = w >> 1, wc = w & 1;
  const int brow = blockIdx.y * 128, bcol = blockIdx.x * 64;
  f32x4 acc[2][2] = {};
  for (int k0 = 0; k0 < Cch; k0 += 64) {
#pragma unroll
    for (int p = 0; p < 2; p++) {
      int idx = tid + p * 512, row = idx >> 3, seg = idx & 7;
      *(u16x8*)&Ah[0][row][seg * 8] = *(const u16x8*)&Ahi[(size_t)(brow + row) * Cch + k0 + seg * 8];
      *(u16x8*)&Ah[1][row][seg * 8] = *(const u16x8*)&Alo[(size_t)(brow + row) * Cch + k0 + seg * 8];
    }
    {
      int row = tid >> 3, seg = tid & 7;
      *(u16x8*)&Bs[0][row][seg * 8] = *(const u16x8*)&Bhi[(size_t)(bcol + row) * Cch + k0 + seg * 8];
      *(u16x8*)&Bs[1][row][seg * 8] = *(const u16x8*)&Blo[(size_t)(bcol + row) * Cch + k0 + seg * 8];
    }
    __syncthreads();
#pragma unroll
    for (int ks = 0; ks < 2; ks++) {
      s16x8 ah[2], al[2], bh[2], bl[2];
#pragma unroll
      for (int ti = 0; ti < 2; ti++) {
        ah[ti] = *(const s16x8*)&Ah[0][wr * 32 + ti * 16 + lr][ks * 32 + e * 8];
        al[ti] = *(const s16x8*)&Ah[1][wr * 32 + ti * 16 + lr][ks * 32 + e * 8];
      }
#pragma unroll
      for (int tj = 0; tj < 2; tj++) {
        bh[tj] = *(const s16x8*)&Bs[0][wc * 32 + tj * 16 + lr][ks * 32 + e * 8];
        bl[tj] = *(const s16x8*)&Bs[1][wc * 32 + tj * 16 + lr][ks * 32 + e * 8];
      }
#pragma unroll
      for (int ti = 0; ti < 2; ti++)
#pragma unroll
        for (int tj = 0; tj < 2; tj++) {
          acc[ti][tj] = __builtin_amdgcn_mfma_f32_16x16x32_bf16(ah[ti], bh[tj], acc[ti][tj], 0, 0, 0);
          acc[ti][tj] = __builtin_amdgcn_mfma_f32_16x16x32_bf16(ah[ti], bl[tj], acc[ti][tj], 0, 0, 0);
          acc[ti][tj] = __builtin_amdgcn_mfma_f32_16x16x32_bf16(al[ti], bh[tj], acc[ti][tj], 0, 0, 0);
        }
    }
    __syncthreads();
  }
#pragma unroll
  for (int ti = 0; ti < 2; ti++)
#pragma unroll
    for (int tj = 0; tj < 2; tj++) {
      int col = bcol + wc * 32 + tj * 16 + lr;
      float bi = bias[col];
#pragma unroll
      for (int r = 0; r < 4; r++) {
        int row = brow + wr * 32 + ti * 16 + e * 4 + r;
        Out[(size_t)row * Cch + col] = acc[ti][tj][r] + bi;
      }
    }
}

// ---------- V normalize + transpose via LDS: Vf[token][C] f32 -> Vt[bh*64+d][t] bf16 ----------
__global__ __launch_bounds__(256) void vnormt_k(const float* __restrict__ Vf,
                                                unsigned short* __restrict__ Vt) {
  __shared__ unsigned short T[64][72];  // [d][token] bf16
  const int tid = threadIdx.x;
  const int t0 = blockIdx.x * 64;
  const int h = blockIdx.y;
  const int tok = tid >> 2;
  const int q = tid & 3;
  const float* src = Vf + (size_t)(t0 + tok) * Cch + h * 64 + q * 16;
  f32x4 v[4];
  float ss = 0.f;
#pragma unroll
  for (int i = 0; i < 4; i++) {
    v[i] = *(const f32x4*)(src + i * 4);
#pragma unroll
    for (int c = 0; c < 4; c++) ss += v[i][c] * v[i][c];
  }
  ss += __shfl_xor(ss, 1);
  ss += __shfl_xor(ss, 2);
  float inv = 1.0f / fmaxf(sqrtf(ss), 1e-12f);
#pragma unroll
  for (int i = 0; i < 4; i++)
#pragma unroll
    for (int c = 0; c < 4; c++)
      T[q * 16 + i * 4 + c][tok] = f2bf(v[i][c] * inv);
  __syncthreads();
  const int d = tid >> 2, s2 = (tid & 3) * 2;
  const int b = t0 >> 11;
  size_t base = ((size_t)((b * Hc + h) * 64 + d)) * Tc + (t0 & 2047);
  *(u16x8*)(Vt + base + s2 * 8)     = *(const u16x8*)&T[d][s2 * 8];
  *(u16x8*)(Vt + base + s2 * 8 + 8) = *(const u16x8*)&T[d][s2 * 8 + 8];
}

// ---------- S = (Q K^T)/8 into causal-compact triangular storage ----------
__global__ __launch_bounds__(512) void sqk_k(const unsigned short* __restrict__ Qp,
    const unsigned short* __restrict__ Kp, float* __restrict__ S, int bh0) {
  __shared__ unsigned short Qs[128][72], Ks[128][72];
  int rt, ct;
  {
    int i = blockIdx.x;
    int r = (int)((sqrtf(8.f * i + 1.f) - 1.f) * 0.5f);
    while ((r + 1) * (r + 2) / 2 <= i) r++;
    while (r * (r + 1) / 2 > i) r--;
    rt = r; ct = i - r * (r + 1) / 2;
  }
  const int bh = bh0 + blockIdx.y, b = bh >> 3, h = bh & 7;
  const int tid = threadIdx.x, w = tid >> 6, lane = tid & 63, e = lane >> 4, lr = lane & 15;
#pragma unroll
  for (int p = 0; p < 2; p++) {
    int idx = tid + p * 512, row = idx >> 3, seg = idx & 7;
    *(u16x8*)&Qs[row][seg * 8] = *(const u16x8*)&Qp[((size_t)(b * Tc + rt * 128 + row)) * Cch + h * 64 + seg * 8];
    *(u16x8*)&Ks[row][seg * 8] = *(const u16x8*)&Kp[((size_t)(b * Tc + ct * 128 + row)) * Cch + h * 64 + seg * 8];
  }
  __syncthreads();
  f32x4 acc[8] = {};
  s16x8 a[2];
#pragma unroll
  for (int ks = 0; ks < 2; ks++) a[ks] = *(const s16x8*)&Qs[w * 16 + lr][ks * 32 + e * 8];
#pragma unroll
  for (int tj = 0; tj < 8; tj++) {
#pragma unroll
    for (int ks = 0; ks < 2; ks++) {
      s16x8 bb = *(const s16x8*)&Ks[tj * 16 + lr][ks * 32 + e * 8];
      acc[tj] = __builtin_amdgcn_mfma_f32_16x16x32_bf16(a[ks], bb, acc[tj], 0, 0, 0);
    }
  }
  float* Srow0 = S + (size_t)(bh - bh0) * TRI_FLOATS + (size_t)tri_i(rt) * 16384;
  const int stride = (rt + 1) * 128;
#pragma unroll
  for (int tj = 0; tj < 8; tj++)
#pragma unroll
    for (int r = 0; r < 4; r++) {
      int row = w * 16 + e * 4 + r;
      Srow0[(size_t)row * stride + ct * 128 + tj * 16 + lr] = acc[tj][r] * 0.125f;
    }
}

// ---------- exact top-64 + softmax; radix-4 descent (2 bits/iter, 3 independent count chains) ----------
// chunk-guarded; LPT block order; writes normalized P bf16 in-place
__global__ __launch_bounds__(512, 4) void sel_k(float* __restrict__ S) {
  int bidr = (int)gridDim.x - 1 - (int)blockIdx.x;   // long rows dispatch first
  int wid = bidr * 8 + (threadIdx.x >> 6);
  int lane = threadIdx.x & 63;
  int bhl = wid >> 11, t = wid & 2047;
  int rt = t >> 7, lrow = t & 127;
  int stride = (rt + 1) * 128;
  float* row = S + (size_t)bhl * TRI_FLOATS + (size_t)tri_i(rt) * 16384 + (size_t)lrow * stride;
  unsigned su[32];
#pragma unroll
  for (int c = 0; c < 8; c++) {
    if (c * 256 < stride) {
      int j0 = c * 256 + lane * 4;
      f32x4 v;
      if (j0 < stride) v = *(const f32x4*)(row + j0);
      else { v[0] = v[1] = v[2] = v[3] = -INFINITY; }
#pragma unroll
      for (int cc = 0; cc < 4; cc++) {
        float x = (j0 + cc <= t) ? v[cc] : -INFINITY;
        unsigned u = __float_as_uint(x);
        su[c * 4 + cc] = (u & 0x80000000u) ? ~u : (u | 0x80000000u);
      }
    } else {
#pragma unroll
      for (int cc = 0; cc < 4; cc++) su[c * 4 + cc] = 0x007FFFFFu;  // map(-inf)
    }
  }
  // radix-4: per pair of bits pick the largest prefix-extension with count >= 64.
  // Equivalent to two binary radix steps; min-refine early exit at cnt==64.
  unsigned lo = 0;
#pragma unroll 1
  for (int b = 30; b >= 0; b -= 2) {
    unsigned cand1 = lo | (1u << b);
    unsigned cand2 = lo | (2u << b);
    unsigned cand3 = lo | (3u << b);
    int c1 = 0, c2 = 0, c3 = 0;
#pragma unroll
    for (int c = 0; c < 8; c++)
      if (c * 256 < stride)
#pragma unroll
        for (int q = 0; q < 4; q++) {
          unsigned s = su[c * 4 + q];
          c1 += (int)__popcll(__ballot(s >= cand1));
          c2 += (int)__popcll(__ballot(s >= cand2));
          c3 += (int)__popcll(__ballot(s >= cand3));
        }
    int cnt = -1;
    if (c3 >= 64)      { lo = cand3; cnt = c3; }
    else if (c2 >= 64) { lo = cand2; cnt = c2; }
    else if (c1 >= 64) { lo = cand1; cnt = c1; }
    if (cnt == 64) {
      unsigned mn = 0xFFFFFFFFu;
#pragma unroll
      for (int c = 0; c < 8; c++)
        if (c * 256 < stride)
#pragma unroll
          for (int q = 0; q < 4; q++) { unsigned x = (su[c * 4 + q] >= lo) ? su[c * 4 + q] : 0xFFFFFFFFu; mn = mn < x ? mn : x; }
#pragma unroll
      for (int o = 32; o; o >>= 1) { unsigned x = (unsigned)__shfl_xor((int)mn, o); mn = mn < x ? mn : x; }
      lo = mn;
      break;
    }
  }
  unsigned mx = 0;
#pragma unroll
  for (int c = 0; c < 8; c++)
    if (c * 256 < stride)
#pragma unroll
      for (int q = 0; q < 4; q++) mx = mx > su[c * 4 + q] ? mx : su[c * 4 + q];
#pragma unroll
  for (int o = 32; o; o >>= 1) { unsigned x = (unsigned)__shfl_xor((int)mx, o); mx = mx > x ? mx : x; }
  float m = su2f(mx);
  float sum = 0.f;
#pragma unroll
  for (int c = 0; c < 8; c++)
    if (c * 256 < stride)
#pragma unroll
      for (int q = 0; q < 4; q++) {
        float v = su2f(su[c * 4 + q]);
        float wv = (su[c * 4 + q] >= lo) ? __expf(v - m) : 0.f;  // exp(-inf)=0
        su[c * 4 + q] = __float_as_uint(wv);
        sum += wv;
      }
  sum = wave_sum_f(sum);
  float inv = 1.f / sum;
  unsigned short* prow = (unsigned short*)row;
#pragma unroll
  for (int c = 0; c < 8; c++) {
    if (c * 256 < stride) {
      int j0 = c * 256 + lane * 4;
      if (j0 < stride) {
        u16x4 pk;
#pragma unroll
        for (int cc = 0; cc < 4; cc++) pk[cc] = f2bf(__uint_as_float(su[c * 4 + cc]) * inv);
        *(u16x4*)(prow + j0) = pk;
      }
    }
  }
}

// ---------- Y = P @ V^T: 64-row blocks, LPT (big rt first), 4 blocks/CU ----------
__global__ __launch_bounds__(512) void pv_k(const float* __restrict__ S,
    const unsigned short* __restrict__ Vt,
    unsigned short* __restrict__ Yhi, unsigned short* __restrict__ Ylo, int bh0) {
  __shared__ unsigned short Ps[64][136];
  __shared__ unsigned short Vs[64][136];
  const int x = blockIdx.x;                    // 0..2*NRT-1
  const int rt = NRT - 1 - (x >> 1);           // big rt dispatched first
  const int half = x & 1;
  const int bh = bh0 + blockIdx.y, b = bh >> 3, h = bh & 7;
  const int tid = threadIdx.x, w = tid >> 6, lane = tid & 63, e = lane >> 4, lr = lane & 15;
  const int stride = (rt + 1) * 128;
  const int rbase = half * 64;                 // local row base within the 128-row tile
  const float* Srow0 = S + (size_t)(bh - bh0) * TRI_FLOATS + (size_t)tri_i(rt) * 16384;
  const int rg = w & 3, dh = w >> 2;           // row-group (16 rows), d-half (32 cols)
  f32x4 acc[2] = {};
  for (int kt = 0; kt <= rt; kt++) {
#pragma unroll
    for (int p = 0; p < 2; p++) {
      int idx = tid + p * 512, pr = idx >> 4, seg = idx & 15;
      const unsigned short* src =
          (const unsigned short*)(Srow0 + (size_t)(rbase + pr) * stride) + kt * 128 + seg * 8;
      *(u16x8*)&Ps[pr][seg * 8] = *(const u16x8*)src;
      *(u16x8*)&Vs[pr][seg * 8] = *(const u16x8*)&Vt[((size_t)(bh * 64 + pr)) * Tc + kt * 128 + seg * 8];
    }
    __syncthreads();
#pragma unroll
    for (int ks = 0; ks < 4; ks++) {
      s16x8 a = *(const s16x8*)&Ps[rg * 16 + lr][ks * 32 + e * 8];
#pragma unroll
      for (int tj = 0; tj < 2; tj++) {
        s16x8 bb = *(const s16x8*)&Vs[dh * 32 + tj * 16 + lr][ks * 32 + e * 8];
        acc[tj] = __builtin_amdgcn_mfma_f32_16x16x32_bf16(a, bb, acc[tj], 0, 0, 0);
      }
    }
    __syncthreads();
  }
#pragma unroll
  for (int tj = 0; tj < 2; tj++)
#pragma unroll
    for (int r = 0; r < 4; r++) {
      int row = rt * 128 + rbase + rg * 16 + e * 4 + r;
      size_t g = ((size_t)(b * Tc + row)) * Cch + h * 64 + dh * 32 + tj * 16 + lr;
      float y = acc[tj][r];
      unsigned short hh = f2bf(y);
      Yhi[g] = hh;
      Ylo[g] = f2bf(y - bf2f(hh));
    }
}

extern "C" void kernel_launch(void* const* d_in, const int* in_sizes, int n_in,
                              void* d_out, int out_size, void* d_ws, size_t ws_size,
                              hipStream_t stream) {
  const float* q  = (const float*)d_in[0];
  // d_in[1] = tgt_mask: pure causal tril, handled analytically
  const float* Wq = (const float*)d_in[2];
  const float* bq = (const float*)d_in[3];
  const float* Wk = (const float*)d_in[4];
  const float* bk = (const float*)d_in[5];
  const float* Wv = (const float*)d_in[6];
  const float* bv = (const float*)d_in[7];
  const float* Wp = (const float*)d_in[8];
  const float* bp = (const float*)d_in[9];
  float* out = (float*)d_out;
  char* ws = (char*)d_ws;
  constexpr size_t MB = 1u << 20;

  unsigned short* Yhi = (unsigned short*)(ws + 0 * MB);   // 4 MB
  unsigned short* Ylo = (unsigned short*)(ws + 4 * MB);   // 4 MB
  unsigned short* Qp  = (unsigned short*)(ws + 8 * MB);   // 4 MB
  unsigned short* Kp  = (unsigned short*)(ws + 12 * MB);  // 4 MB
  unsigned short* Vt  = (unsigned short*)(ws + 16 * MB);  // 4 MB
  unsigned short* wsp = (unsigned short*)(ws + 20 * MB);  // 8 x 512 KB weight splits
  float* Sb = (float*)(ws + 24 * MB);                     // S/P region (chunked)
  float* Vf = (float*)(ws + 24 * MB);                     // overlays S (consumed first)

  int nbh = NBH;
  while (nbh > 1 && 24 * MB + TRI_FLOATS * 4 * (size_t)nbh > ws_size) nbh >>= 1;

  splitT4_k<<<dim3(8, 8, 4), 256, 0, stream>>>(Wq, Wk, Wv, Wp, wsp);

  gemm3w_qkv_k<<<dim3(Cch / 64, BT / 128, 3), 512, 0, stream>>>(
      q, wsp, bq, bk, bv, Qp, Kp, Vf);
  vnormt_k<<<dim3(BT / 64, Hc), 256, 0, stream>>>(Vf, Vt);

  for (int c = 0; c < NBH / nbh; c++) {
    int bh0 = c * nbh;
    sqk_k<<<dim3(NTRI, nbh), 512, 0, stream>>>(Qp, Kp, Sb, bh0);
    sel_k<<<nbh * 256, 512, 0, stream>>>(Sb);
    pv_k<<<dim3(2 * NRT, nbh), 512, 0, stream>>>(Sb, Vt, Yhi, Ylo, bh0);
  }

  gemm3w_out_k<<<dim3(Cch / 64, BT / 128), 512, 0, stream>>>(
      Yhi, Ylo, wsp + (size_t)6 * 262144, wsp + (size_t)7 * 262144, bp, out);
}

// Round 15
// 209.953 us; speedup vs baseline: 1.0363x; 1.0363x over previous
//
#include <hip/hip_runtime.h>
#include <cstdint>
#include <math.h>

static constexpr int Bc = 2, Tc = 2048, Cch = 512, Hc = 8;
static constexpr int BT = Bc * Tc;          // 4096
static constexpr int NBH = Bc * Hc;         // 16
static constexpr int NRT = Tc / 128;        // 16 row-tiles per (b,h)
static constexpr int NTRI = NRT * (NRT + 1) / 2;  // 136 causal blocks
static constexpr size_t TRI_FLOATS = (size_t)NTRI * 16384;  // f32 per (b,h)

typedef float f32x4 __attribute__((ext_vector_type(4)));
typedef short s16x8 __attribute__((ext_vector_type(8)));
typedef unsigned short u16x8 __attribute__((ext_vector_type(8)));
typedef unsigned short u16x4 __attribute__((ext_vector_type(4)));

__device__ __host__ inline constexpr int tri_i(int r) { return r * (r + 1) / 2; }

__device__ inline float wave_sum_f(float x) {
#pragma unroll
  for (int o = 32; o; o >>= 1) x += __shfl_xor(x, o);
  return x;
}
__device__ inline unsigned short f2bf(float x) {  // RNE f32->bf16 (finite)
  unsigned u = __float_as_uint(x);
  return (unsigned short)((u + 0x7FFFu + ((u >> 16) & 1u)) >> 16);
}
__device__ inline float bf2f(unsigned short h) { return __uint_as_float(((unsigned)h) << 16); }
__device__ inline float su2f(unsigned s) {  // inverse order-preserving map
  unsigned u = (s & 0x80000000u) ? (s ^ 0x80000000u) : ~s;
  return __uint_as_float(u);
}

// ---------- split + transpose all 4 weights: W[k][n] f32 -> WT[n][k] bf16 hi/lo ----------
__global__ __launch_bounds__(256) void splitT4_k(const float* __restrict__ Wq,
    const float* __restrict__ Wk, const float* __restrict__ Wv,
    const float* __restrict__ Wp, unsigned short* __restrict__ wsp) {
  const int z = blockIdx.z;
  const float* W = (z == 0) ? Wq : (z == 1) ? Wk : (z == 2) ? Wv : Wp;
  unsigned short* hiT = wsp + (size_t)z * 524288;
  unsigned short* loT = hiT + 262144;
  __shared__ float t[64][65];
  const int tid = threadIdx.x;
  const int k0 = blockIdx.x * 64, n0 = blockIdx.y * 64;
#pragma unroll
  for (int p = 0; p < 4; p++) {
    int idx = tid + p * 256, kk = idx >> 4, n4 = idx & 15;
    f32x4 v = *(const f32x4*)&W[(size_t)(k0 + kk) * Cch + n0 + n4 * 4];
    t[kk][n4 * 4 + 0] = v[0]; t[kk][n4 * 4 + 1] = v[1];
    t[kk][n4 * 4 + 2] = v[2]; t[kk][n4 * 4 + 3] = v[3];
  }
  __syncthreads();
  {
    int n = tid >> 2, ks = tid & 3;
    u16x8 h0, h1, l0, l1;
#pragma unroll
    for (int kk = 0; kk < 8; kk++) {
      float x = t[ks * 16 + kk][n];
      unsigned short hh = f2bf(x);
      h0[kk] = hh; l0[kk] = f2bf(x - bf2f(hh));
      float y = t[ks * 16 + 8 + kk][n];
      unsigned short hy = f2bf(y);
      h1[kk] = hy; l1[kk] = f2bf(y - bf2f(hy));
    }
    size_t base = (size_t)(n0 + n) * Cch + k0 + ks * 16;
    *(u16x8*)(hiT + base) = h0; *(u16x8*)(hiT + base + 8) = h1;
    *(u16x8*)(loT + base) = l0; *(u16x8*)(loT + base + 8) = l1;
  }
}

// ---------- merged Q/K/V projection: reads q f32, splits hi/lo inline while staging ----------
__global__ __launch_bounds__(512) void gemm3w_qkv_k(
    const float* __restrict__ Aq, const unsigned short* __restrict__ wsp,
    const float* __restrict__ bq, const float* __restrict__ bk, const float* __restrict__ bv,
    unsigned short* __restrict__ Qp, unsigned short* __restrict__ Kp, float* __restrict__ Vf) {
  const int z = blockIdx.z;
  const unsigned short* Bhi = wsp + (size_t)z * 524288;
  const unsigned short* Blo = Bhi + 262144;
  const float* bias = (z == 0) ? bq : (z == 1) ? bk : bv;
  __shared__ unsigned short Ah[2][128][72];
  __shared__ unsigned short Bs[2][64][72];
  const int tid = threadIdx.x;
  const int w = tid >> 6, lane = tid & 63, e = lane >> 4, lr = lane & 15;
  const int wr = w >> 1, wc = w & 1;                 // 4x2 wave grid
  const int brow = blockIdx.y * 128, bcol = blockIdx.x * 64;
  f32x4 acc[2][2] = {};
  for (int k0 = 0; k0 < Cch; k0 += 64) {
#pragma unroll
    for (int p = 0; p < 4; p++) {
      int idx = tid + p * 512, row = idx >> 4, seg = idx & 15;  // 128 rows x 16 f32x4 segs
      f32x4 v = *(const f32x4*)&Aq[(size_t)(brow + row) * Cch + k0 + seg * 4];
      u16x4 hv, lv;
#pragma unroll
      for (int c = 0; c < 4; c++) {
        unsigned short hh = f2bf(v[c]);
        hv[c] = hh;
        lv[c] = f2bf(v[c] - bf2f(hh));
      }
      *(u16x4*)&Ah[0][row][seg * 4] = hv;
      *(u16x4*)&Ah[1][row][seg * 4] = lv;
    }
    {
      int row = tid >> 3, seg = tid & 7;
      *(u16x8*)&Bs[0][row][seg * 8] = *(const u16x8*)&Bhi[(size_t)(bcol + row) * Cch + k0 + seg * 8];
      *(u16x8*)&Bs[1][row][seg * 8] = *(const u16x8*)&Blo[(size_t)(bcol + row) * Cch + k0 + seg * 8];
    }
    __syncthreads();
#pragma unroll
    for (int ks = 0; ks < 2; ks++) {
      s16x8 ah[2], al[2], bh[2], bl[2];
#pragma unroll
      for (int ti = 0; ti < 2; ti++) {
        ah[ti] = *(const s16x8*)&Ah[0][wr * 32 + ti * 16 + lr][ks * 32 + e * 8];
        al[ti] = *(const s16x8*)&Ah[1][wr * 32 + ti * 16 + lr][ks * 32 + e * 8];
      }
#pragma unroll
      for (int tj = 0; tj < 2; tj++) {
        bh[tj] = *(const s16x8*)&Bs[0][wc * 32 + tj * 16 + lr][ks * 32 + e * 8];
        bl[tj] = *(const s16x8*)&Bs[1][wc * 32 + tj * 16 + lr][ks * 32 + e * 8];
      }
#pragma unroll
      for (int ti = 0; ti < 2; ti++)
#pragma unroll
        for (int tj = 0; tj < 2; tj++) {
          acc[ti][tj] = __builtin_amdgcn_mfma_f32_16x16x32_bf16(ah[ti], bh[tj], acc[ti][tj], 0, 0, 0);
          acc[ti][tj] = __builtin_amdgcn_mfma_f32_16x16x32_bf16(ah[ti], bl[tj], acc[ti][tj], 0, 0, 0);
          acc[ti][tj] = __builtin_amdgcn_mfma_f32_16x16x32_bf16(al[ti], bh[tj], acc[ti][tj], 0, 0, 0);
        }
    }
    __syncthreads();
  }
#pragma unroll
  for (int ti = 0; ti < 2; ti++)
#pragma unroll
    for (int tj = 0; tj < 2; tj++) {
      int col = bcol + wc * 32 + tj * 16 + lr;
      float bi = bias[col];
#pragma unroll
      for (int r = 0; r < 4; r++) {
        int row = brow + wr * 32 + ti * 16 + e * 4 + r;
        float v = acc[ti][tj][r] + bi;
        size_t g = (size_t)row * Cch + col;
        if (z == 0) Qp[g] = f2bf(v);
        else if (z == 1) Kp[g] = f2bf(v);
        else Vf[g] = v;
      }
    }
}

// ---------- output projection: A pre-split (Yhi/Ylo), f32 out ----------
__global__ __launch_bounds__(512) void gemm3w_out_k(
    const unsigned short* __restrict__ Ahi, const unsigned short* __restrict__ Alo,
    const unsigned short* __restrict__ Bhi, const unsigned short* __restrict__ Blo,
    const float* __restrict__ bias, float* __restrict__ Out) {
  __shared__ unsigned short Ah[2][128][72];
  __shared__ unsigned short Bs[2][64][72];
  const int tid = threadIdx.x;
  const int w = tid >> 6, lane = tid & 63, e = lane >> 4, lr = lane & 15;
  const int wr = w >> 1, wc = w & 1;
  const int brow = blockIdx.y * 128, bcol = blockIdx.x * 64;
  f32x4 acc[2][2] = {};
  for (int k0 = 0; k0 < Cch; k0 += 64) {
#pragma unroll
    for (int p = 0; p < 2; p++) {
      int idx = tid + p * 512, row = idx >> 3, seg = idx & 7;
      *(u16x8*)&Ah[0][row][seg * 8] = *(const u16x8*)&Ahi[(size_t)(brow + row) * Cch + k0 + seg * 8];
      *(u16x8*)&Ah[1][row][seg * 8] = *(const u16x8*)&Alo[(size_t)(brow + row) * Cch + k0 + seg * 8];
    }
    {
      int row = tid >> 3, seg = tid & 7;
      *(u16x8*)&Bs[0][row][seg * 8] = *(const u16x8*)&Bhi[(size_t)(bcol + row) * Cch + k0 + seg * 8];
      *(u16x8*)&Bs[1][row][seg * 8] = *(const u16x8*)&Blo[(size_t)(bcol + row) * Cch + k0 + seg * 8];
    }
    __syncthreads();
#pragma unroll
    for (int ks = 0; ks < 2; ks++) {
      s16x8 ah[2], al[2], bh[2], bl[2];
#pragma unroll
      for (int ti = 0; ti < 2; ti++) {
        ah[ti] = *(const s16x8*)&Ah[0][wr * 32 + ti * 16 + lr][ks * 32 + e * 8];
        al[ti] = *(const s16x8*)&Ah[1][wr * 32 + ti * 16 + lr][ks * 32 + e * 8];
      }
#pragma unroll
      for (int tj = 0; tj < 2; tj++) {
        bh[tj] = *(const s16x8*)&Bs[0][wc * 32 + tj * 16 + lr][ks * 32 + e * 8];
        bl[tj] = *(const s16x8*)&Bs[1][wc * 32 + tj * 16 + lr][ks * 32 + e * 8];
      }
#pragma unroll
      for (int ti = 0; ti < 2; ti++)
#pragma unroll
        for (int tj = 0; tj < 2; tj++) {
          acc[ti][tj] = __builtin_amdgcn_mfma_f32_16x16x32_bf16(ah[ti], bh[tj], acc[ti][tj], 0, 0, 0);
          acc[ti][tj] = __builtin_amdgcn_mfma_f32_16x16x32_bf16(ah[ti], bl[tj], acc[ti][tj], 0, 0, 0);
          acc[ti][tj] = __builtin_amdgcn_mfma_f32_16x16x32_bf16(al[ti], bh[tj], acc[ti][tj], 0, 0, 0);
        }
    }
    __syncthreads();
  }
#pragma unroll
  for (int ti = 0; ti < 2; ti++)
#pragma unroll
    for (int tj = 0; tj < 2; tj++) {
      int col = bcol + wc * 32 + tj * 16 + lr;
      float bi = bias[col];
#pragma unroll
      for (int r = 0; r < 4; r++) {
        int row = brow + wr * 32 + ti * 16 + e * 4 + r;
        Out[(size_t)row * Cch + col] = acc[ti][tj][r] + bi;
      }
    }
}

// ---------- V normalize + transpose via LDS: Vf[token][C] f32 -> Vt[bh*64+d][t] bf16 ----------
__global__ __launch_bounds__(256) void vnormt_k(const float* __restrict__ Vf,
                                                unsigned short* __restrict__ Vt) {
  __shared__ unsigned short T[64][72];  // [d][token] bf16
  const int tid = threadIdx.x;
  const int t0 = blockIdx.x * 64;
  const int h = blockIdx.y;
  const int tok = tid >> 2;
  const int q = tid & 3;
  const float* src = Vf + (size_t)(t0 + tok) * Cch + h * 64 + q * 16;
  f32x4 v[4];
  float ss = 0.f;
#pragma unroll
  for (int i = 0; i < 4; i++) {
    v[i] = *(const f32x4*)(src + i * 4);
#pragma unroll
    for (int c = 0; c < 4; c++) ss += v[i][c] * v[i][c];
  }
  ss += __shfl_xor(ss, 1);
  ss += __shfl_xor(ss, 2);
  float inv = 1.0f / fmaxf(sqrtf(ss), 1e-12f);
#pragma unroll
  for (int i = 0; i < 4; i++)
#pragma unroll
    for (int c = 0; c < 4; c++)
      T[q * 16 + i * 4 + c][tok] = f2bf(v[i][c] * inv);
  __syncthreads();
  const int d = tid >> 2, s2 = (tid & 3) * 2;
  const int b = t0 >> 11;
  size_t base = ((size_t)((b * Hc + h) * 64 + d)) * Tc + (t0 & 2047);
  *(u16x8*)(Vt + base + s2 * 8)     = *(const u16x8*)&T[d][s2 * 8];
  *(u16x8*)(Vt + base + s2 * 8 + 8) = *(const u16x8*)&T[d][s2 * 8 + 8];
}

// ---------- S = (Q K^T)/8 into causal-compact triangular storage ----------
__global__ __launch_bounds__(512) void sqk_k(const unsigned short* __restrict__ Qp,
    const unsigned short* __restrict__ Kp, float* __restrict__ S, int bh0) {
  __shared__ unsigned short Qs[128][72], Ks[128][72];
  int rt, ct;
  {
    int i = blockIdx.x;
    int r = (int)((sqrtf(8.f * i + 1.f) - 1.f) * 0.5f);
    while ((r + 1) * (r + 2) / 2 <= i) r++;
    while (r * (r + 1) / 2 > i) r--;
    rt = r; ct = i - r * (r + 1) / 2;
  }
  const int bh = bh0 + blockIdx.y, b = bh >> 3, h = bh & 7;
  const int tid = threadIdx.x, w = tid >> 6, lane = tid & 63, e = lane >> 4, lr = lane & 15;
#pragma unroll
  for (int p = 0; p < 2; p++) {
    int idx = tid + p * 512, row = idx >> 3, seg = idx & 7;
    *(u16x8*)&Qs[row][seg * 8] = *(const u16x8*)&Qp[((size_t)(b * Tc + rt * 128 + row)) * Cch + h * 64 + seg * 8];
    *(u16x8*)&Ks[row][seg * 8] = *(const u16x8*)&Kp[((size_t)(b * Tc + ct * 128 + row)) * Cch + h * 64 + seg * 8];
  }
  __syncthreads();
  f32x4 acc[8] = {};
  s16x8 a[2];
#pragma unroll
  for (int ks = 0; ks < 2; ks++) a[ks] = *(const s16x8*)&Qs[w * 16 + lr][ks * 32 + e * 8];
#pragma unroll
  for (int tj = 0; tj < 8; tj++) {
#pragma unroll
    for (int ks = 0; ks < 2; ks++) {
      s16x8 bb = *(const s16x8*)&Ks[tj * 16 + lr][ks * 32 + e * 8];
      acc[tj] = __builtin_amdgcn_mfma_f32_16x16x32_bf16(a[ks], bb, acc[tj], 0, 0, 0);
    }
  }
  float* Srow0 = S + (size_t)(bh - bh0) * TRI_FLOATS + (size_t)tri_i(rt) * 16384;
  const int stride = (rt + 1) * 128;
#pragma unroll
  for (int tj = 0; tj < 8; tj++)
#pragma unroll
    for (int r = 0; r < 4; r++) {
      int row = w * 16 + e * 4 + r;
      Srow0[(size_t)row * stride + ct * 128 + tj * 16 + lr] = acc[tj][r] * 0.125f;
    }
}

// ---------- exact top-64 + softmax; writes normalized P bf16 in-place ----------
// chunk-guarded; LPT block order (R11/R13-validated form — 1 row per wave)
__global__ __launch_bounds__(512, 4) void sel_k(float* __restrict__ S) {
  int bidr = (int)gridDim.x - 1 - (int)blockIdx.x;   // long rows dispatch first
  int wid = bidr * 8 + (threadIdx.x >> 6);
  int lane = threadIdx.x & 63;
  int bhl = wid >> 11, t = wid & 2047;
  int rt = t >> 7, lrow = t & 127;
  int stride = (rt + 1) * 128;
  float* row = S + (size_t)bhl * TRI_FLOATS + (size_t)tri_i(rt) * 16384 + (size_t)lrow * stride;
  unsigned su[32];
#pragma unroll
  for (int c = 0; c < 8; c++) {
    if (c * 256 < stride) {
      int j0 = c * 256 + lane * 4;
      f32x4 v;
      if (j0 < stride) v = *(const f32x4*)(row + j0);
      else { v[0] = v[1] = v[2] = v[3] = -INFINITY; }
#pragma unroll
      for (int cc = 0; cc < 4; cc++) {
        float x = (j0 + cc <= t) ? v[cc] : -INFINITY;
        unsigned u = __float_as_uint(x);
        su[c * 4 + cc] = (u & 0x80000000u) ? ~u : (u | 0x80000000u);
      }
    } else {
#pragma unroll
      for (int cc = 0; cc < 4; cc++) su[c * 4 + cc] = 0x007FFFFFu;  // map(-inf)
    }
  }
  // radix search for max lo with count(su >= lo) >= 64; early-exit min-refine at cnt==64
  unsigned lo = 0;
#pragma unroll 1
  for (int bit = 31; bit >= 0; bit--) {
    unsigned cand = lo | (1u << bit);
    int cnt = 0;
#pragma unroll
    for (int c = 0; c < 8; c++)
      if (c * 256 < stride)
#pragma unroll
        for (int q = 0; q < 4; q++)
          cnt += (int)__popcll(__ballot(su[c * 4 + q] >= cand));
    if (cnt >= 64) {
      lo = cand;
      if (cnt == 64) {
        unsigned mn = 0xFFFFFFFFu;
#pragma unroll
        for (int c = 0; c < 8; c++)
          if (c * 256 < stride)
#pragma unroll
            for (int q = 0; q < 4; q++) { unsigned x = (su[c * 4 + q] >= cand) ? su[c * 4 + q] : 0xFFFFFFFFu; mn = mn < x ? mn : x; }
#pragma unroll
        for (int o = 32; o; o >>= 1) { unsigned x = (unsigned)__shfl_xor((int)mn, o); mn = mn < x ? mn : x; }
        lo = mn;
        break;
      }
    }
  }
  unsigned mx = 0;
#pragma unroll
  for (int c = 0; c < 8; c++)
    if (c * 256 < stride)
#pragma unroll
      for (int q = 0; q < 4; q++) mx = mx > su[c * 4 + q] ? mx : su[c * 4 + q];
#pragma unroll
  for (int o = 32; o; o >>= 1) { unsigned x = (unsigned)__shfl_xor((int)mx, o); mx = mx > x ? mx : x; }
  float m = su2f(mx);
  float sum = 0.f;
#pragma unroll
  for (int c = 0; c < 8; c++)
    if (c * 256 < stride)
#pragma unroll
      for (int q = 0; q < 4; q++) {
        float v = su2f(su[c * 4 + q]);
        float wv = (su[c * 4 + q] >= lo) ? __expf(v - m) : 0.f;  // exp(-inf)=0
        su[c * 4 + q] = __float_as_uint(wv);
        sum += wv;
      }
  sum = wave_sum_f(sum);
  float inv = 1.f / sum;
  unsigned short* prow = (unsigned short*)row;
#pragma unroll
  for (int c = 0; c < 8; c++) {
    if (c * 256 < stride) {
      int j0 = c * 256 + lane * 4;
      if (j0 < stride) {
        u16x4 pk;
#pragma unroll
        for (int cc = 0; cc < 4; cc++) pk[cc] = f2bf(__uint_as_float(su[c * 4 + cc]) * inv);
        *(u16x4*)(prow + j0) = pk;
      }
    }
  }
}

// ---------- Y = P @ V^T: 32-row blocks, LPT (big rt first), full 4-blocks/CU fill ----------
__global__ __launch_bounds__(512) void pv_k(const float* __restrict__ S,
    const unsigned short* __restrict__ Vt,
    unsigned short* __restrict__ Yhi, unsigned short* __restrict__ Ylo, int bh0) {
  __shared__ unsigned short Ps[32][136];
  __shared__ unsigned short Vs[64][136];
  const int x = blockIdx.x;                    // 0..4*NRT-1
  const int rt = NRT - 1 - (x >> 2);           // big rt dispatched first
  const int qh = x & 3;
  const int bh = bh0 + blockIdx.y, b = bh >> 3, h = bh & 7;
  const int tid = threadIdx.x, w = tid >> 6, lane = tid & 63, e = lane >> 4, lr = lane & 15;
  const int stride = (rt + 1) * 128;
  const int rbase = qh * 32;                   // local row base within the 128-row tile
  const float* Srow0 = S + (size_t)(bh - bh0) * TRI_FLOATS + (size_t)tri_i(rt) * 16384;
  const int rg = w & 1, dh = w >> 1;           // 2 row-groups (16 rows) x 4 col-quarters (16 cols)
  f32x4 acc = {};
  for (int kt = 0; kt <= rt; kt++) {
    {
      int pr = tid >> 4, seg = tid & 15;       // 32 rows x 16 segs = 512
      const unsigned short* src =
          (const unsigned short*)(Srow0 + (size_t)(rbase + pr) * stride) + kt * 128 + seg * 8;
      *(u16x8*)&Ps[pr][seg * 8] = *(const u16x8*)src;
    }
#pragma unroll
    for (int p = 0; p < 2; p++) {
      int idx = tid + p * 512, d = idx >> 4, seg = idx & 15;  // 64 rows x 16 segs
      *(u16x8*)&Vs[d][seg * 8] = *(const u16x8*)&Vt[((size_t)(bh * 64 + d)) * Tc + kt * 128 + seg * 8];
    }
    __syncthreads();
#pragma unroll
    for (int ks = 0; ks < 4; ks++) {
      s16x8 a = *(const s16x8*)&Ps[rg * 16 + lr][ks * 32 + e * 8];
      s16x8 bb = *(const s16x8*)&Vs[dh * 16 + lr][ks * 32 + e * 8];
      acc = __builtin_amdgcn_mfma_f32_16x16x32_bf16(a, bb, acc, 0, 0, 0);
    }
    __syncthreads();
  }
#pragma unroll
  for (int r = 0; r < 4; r++) {
    int row = rt * 128 + rbase + rg * 16 + e * 4 + r;
    size_t g = ((size_t)(b * Tc + row)) * Cch + h * 64 + dh * 16 + lr;
    float y = acc[r];
    unsigned short hh = f2bf(y);
    Yhi[g] = hh;
    Ylo[g] = f2bf(y - bf2f(hh));
  }
}

extern "C" void kernel_launch(void* const* d_in, const int* in_sizes, int n_in,
                              void* d_out, int out_size, void* d_ws, size_t ws_size,
                              hipStream_t stream) {
  const float* q  = (const float*)d_in[0];
  // d_in[1] = tgt_mask: pure causal tril, handled analytically
  const float* Wq = (const float*)d_in[2];
  const float* bq = (const float*)d_in[3];
  const float* Wk = (const float*)d_in[4];
  const float* bk = (const float*)d_in[5];
  const float* Wv = (const float*)d_in[6];
  const float* bv = (const float*)d_in[7];
  const float* Wp = (const float*)d_in[8];
  const float* bp = (const float*)d_in[9];
  float* out = (float*)d_out;
  char* ws = (char*)d_ws;
  constexpr size_t MB = 1u << 20;

  unsigned short* Yhi = (unsigned short*)(ws + 0 * MB);   // 4 MB
  unsigned short* Ylo = (unsigned short*)(ws + 4 * MB);   // 4 MB
  unsigned short* Qp  = (unsigned short*)(ws + 8 * MB);   // 4 MB
  unsigned short* Kp  = (unsigned short*)(ws + 12 * MB);  // 4 MB
  unsigned short* Vt  = (unsigned short*)(ws + 16 * MB);  // 4 MB
  unsigned short* wsp = (unsigned short*)(ws + 20 * MB);  // 8 x 512 KB weight splits
  float* Sb = (float*)(ws + 24 * MB);                     // S/P region (chunked)
  float* Vf = (float*)(ws + 24 * MB);                     // overlays S (consumed first)

  int nbh = NBH;
  while (nbh > 1 && 24 * MB + TRI_FLOATS * 4 * (size_t)nbh > ws_size) nbh >>= 1;

  splitT4_k<<<dim3(8, 8, 4), 256, 0, stream>>>(Wq, Wk, Wv, Wp, wsp);

  gemm3w_qkv_k<<<dim3(Cch / 64, BT / 128, 3), 512, 0, stream>>>(
      q, wsp, bq, bk, bv, Qp, Kp, Vf);
  vnormt_k<<<dim3(BT / 64, Hc), 256, 0, stream>>>(Vf, Vt);

  for (int c = 0; c < NBH / nbh; c++) {
    int bh0 = c * nbh;
    sqk_k<<<dim3(NTRI, nbh), 512, 0, stream>>>(Qp, Kp, Sb, bh0);
    sel_k<<<nbh * 256, 512, 0, stream>>>(Sb);
    pv_k<<<dim3(4 * NRT, nbh), 512, 0, stream>>>(Sb, Vt, Yhi, Ylo, bh0);
  }

  gemm3w_out_k<<<dim3(Cch / 64, BT / 128), 512, 0, stream>>>(
      Yhi, Ylo, wsp + (size_t)6 * 262144, wsp + (size_t)7 * 262144, bp, out);
}

// Round 16
// 203.136 us; speedup vs baseline: 1.0711x; 1.0336x over previous
//
#include <hip/hip_runtime.h>
#include <cstdint>
#include <math.h>

static constexpr int Bc = 2, Tc = 2048, Cch = 512, Hc = 8;
static constexpr int BT = Bc * Tc;          // 4096
static constexpr int NBH = Bc * Hc;         // 16
static constexpr int NRT = Tc / 128;        // 16 row-tiles per (b,h)
static constexpr int NTRI = NRT * (NRT + 1) / 2;  // 136 causal blocks
static constexpr size_t TRI_FLOATS = (size_t)NTRI * 16384;  // f32 per (b,h)

typedef float f32x4 __attribute__((ext_vector_type(4)));
typedef short s16x8 __attribute__((ext_vector_type(8)));
typedef unsigned short u16x8 __attribute__((ext_vector_type(8)));
typedef unsigned short u16x4 __attribute__((ext_vector_type(4)));

__device__ __host__ inline constexpr int tri_i(int r) { return r * (r + 1) / 2; }

__device__ inline float wave_sum_f(float x) {
#pragma unroll
  for (int o = 32; o; o >>= 1) x += __shfl_xor(x, o);
  return x;
}
__device__ inline unsigned short f2bf(float x) {  // RNE f32->bf16 (finite)
  unsigned u = __float_as_uint(x);
  return (unsigned short)((u + 0x7FFFu + ((u >> 16) & 1u)) >> 16);
}
__device__ inline float bf2f(unsigned short h) { return __uint_as_float(((unsigned)h) << 16); }
__device__ inline float su2f(unsigned s) {  // inverse order-preserving map
  unsigned u = (s & 0x80000000u) ? (s ^ 0x80000000u) : ~s;
  return __uint_as_float(u);
}

// ---------- split + transpose all 4 weights: W[k][n] f32 -> WT[n][k] bf16 hi/lo ----------
__global__ __launch_bounds__(256) void splitT4_k(const float* __restrict__ Wq,
    const float* __restrict__ Wk, const float* __restrict__ Wv,
    const float* __restrict__ Wp, unsigned short* __restrict__ wsp) {
  const int z = blockIdx.z;
  const float* W = (z == 0) ? Wq : (z == 1) ? Wk : (z == 2) ? Wv : Wp;
  unsigned short* hiT = wsp + (size_t)z * 524288;
  unsigned short* loT = hiT + 262144;
  __shared__ float t[64][65];
  const int tid = threadIdx.x;
  const int k0 = blockIdx.x * 64, n0 = blockIdx.y * 64;
#pragma unroll
  for (int p = 0; p < 4; p++) {
    int idx = tid + p * 256, kk = idx >> 4, n4 = idx & 15;
    f32x4 v = *(const f32x4*)&W[(size_t)(k0 + kk) * Cch + n0 + n4 * 4];
    t[kk][n4 * 4 + 0] = v[0]; t[kk][n4 * 4 + 1] = v[1];
    t[kk][n4 * 4 + 2] = v[2]; t[kk][n4 * 4 + 3] = v[3];
  }
  __syncthreads();
  {
    int n = tid >> 2, ks = tid & 3;
    u16x8 h0, h1, l0, l1;
#pragma unroll
    for (int kk = 0; kk < 8; kk++) {
      float x = t[ks * 16 + kk][n];
      unsigned short hh = f2bf(x);
      h0[kk] = hh; l0[kk] = f2bf(x - bf2f(hh));
      float y = t[ks * 16 + 8 + kk][n];
      unsigned short hy = f2bf(y);
      h1[kk] = hy; l1[kk] = f2bf(y - bf2f(hy));
    }
    size_t base = (size_t)(n0 + n) * Cch + k0 + ks * 16;
    *(u16x8*)(hiT + base) = h0; *(u16x8*)(hiT + base + 8) = h1;
    *(u16x8*)(loT + base) = l0; *(u16x8*)(loT + base + 8) = l1;
  }
}

// ---------- merged Q/K/V projection: reads q f32, splits hi/lo inline while staging ----------
__global__ __launch_bounds__(512) void gemm3w_qkv_k(
    const float* __restrict__ Aq, const unsigned short* __restrict__ wsp,
    const float* __restrict__ bq, const float* __restrict__ bk, const float* __restrict__ bv,
    unsigned short* __restrict__ Qp, unsigned short* __restrict__ Kp, float* __restrict__ Vf) {
  const int z = blockIdx.z;
  const unsigned short* Bhi = wsp + (size_t)z * 524288;
  const unsigned short* Blo = Bhi + 262144;
  const float* bias = (z == 0) ? bq : (z == 1) ? bk : bv;
  __shared__ unsigned short Ah[2][128][72];
  __shared__ unsigned short Bs[2][64][72];
  const int tid = threadIdx.x;
  const int w = tid >> 6, lane = tid & 63, e = lane >> 4, lr = lane & 15;
  const int wr = w >> 1, wc = w & 1;                 // 4x2 wave grid
  const int brow = blockIdx.y * 128, bcol = blockIdx.x * 64;
  f32x4 acc[2][2] = {};
  for (int k0 = 0; k0 < Cch; k0 += 64) {
#pragma unroll
    for (int p = 0; p < 4; p++) {
      int idx = tid + p * 512, row = idx >> 4, seg = idx & 15;  // 128 rows x 16 f32x4 segs
      f32x4 v = *(const f32x4*)&Aq[(size_t)(brow + row) * Cch + k0 + seg * 4];
      u16x4 hv, lv;
#pragma unroll
      for (int c = 0; c < 4; c++) {
        unsigned short hh = f2bf(v[c]);
        hv[c] = hh;
        lv[c] = f2bf(v[c] - bf2f(hh));
      }
      *(u16x4*)&Ah[0][row][seg * 4] = hv;
      *(u16x4*)&Ah[1][row][seg * 4] = lv;
    }
    {
      int row = tid >> 3, seg = tid & 7;
      *(u16x8*)&Bs[0][row][seg * 8] = *(const u16x8*)&Bhi[(size_t)(bcol + row) * Cch + k0 + seg * 8];
      *(u16x8*)&Bs[1][row][seg * 8] = *(const u16x8*)&Blo[(size_t)(bcol + row) * Cch + k0 + seg * 8];
    }
    __syncthreads();
#pragma unroll
    for (int ks = 0; ks < 2; ks++) {
      s16x8 ah[2], al[2], bh[2], bl[2];
#pragma unroll
      for (int ti = 0; ti < 2; ti++) {
        ah[ti] = *(const s16x8*)&Ah[0][wr * 32 + ti * 16 + lr][ks * 32 + e * 8];
        al[ti] = *(const s16x8*)&Ah[1][wr * 32 + ti * 16 + lr][ks * 32 + e * 8];
      }
#pragma unroll
      for (int tj = 0; tj < 2; tj++) {
        bh[tj] = *(const s16x8*)&Bs[0][wc * 32 + tj * 16 + lr][ks * 32 + e * 8];
        bl[tj] = *(const s16x8*)&Bs[1][wc * 32 + tj * 16 + lr][ks * 32 + e * 8];
      }
#pragma unroll
      for (int ti = 0; ti < 2; ti++)
#pragma unroll
        for (int tj = 0; tj < 2; tj++) {
          acc[ti][tj] = __builtin_amdgcn_mfma_f32_16x16x32_bf16(ah[ti], bh[tj], acc[ti][tj], 0, 0, 0);
          acc[ti][tj] = __builtin_amdgcn_mfma_f32_16x16x32_bf16(ah[ti], bl[tj], acc[ti][tj], 0, 0, 0);
          acc[ti][tj] = __builtin_amdgcn_mfma_f32_16x16x32_bf16(al[ti], bh[tj], acc[ti][tj], 0, 0, 0);
        }
    }
    __syncthreads();
  }
#pragma unroll
  for (int ti = 0; ti < 2; ti++)
#pragma unroll
    for (int tj = 0; tj < 2; tj++) {
      int col = bcol + wc * 32 + tj * 16 + lr;
      float bi = bias[col];
#pragma unroll
      for (int r = 0; r < 4; r++) {
        int row = brow + wr * 32 + ti * 16 + e * 4 + r;
        float v = acc[ti][tj][r] + bi;
        size_t g = (size_t)row * Cch + col;
        if (z == 0) Qp[g] = f2bf(v);
        else if (z == 1) Kp[g] = f2bf(v);
        else Vf[g] = v;
      }
    }
}

// ---------- output projection: A pre-split (Yhi/Ylo), f32 out ----------
__global__ __launch_bounds__(512) void gemm3w_out_k(
    const unsigned short* __restrict__ Ahi, const unsigned short* __restrict__ Alo,
    const unsigned short* __restrict__ Bhi, const unsigned short* __restrict__ Blo,
    const float* __restrict__ bias, float* __restrict__ Out) {
  __shared__ unsigned short Ah[2][128][72];
  __shared__ unsigned short Bs[2][64][72];
  const int tid = threadIdx.x;
  const int w = tid >> 6, lane = tid & 63, e = lane >> 4, lr = lane & 15;
  const int wr = w >> 1, wc = w & 1;
  const int brow = blockIdx.y * 128, bcol = blockIdx.x * 64;
  f32x4 acc[2][2] = {};
  for (int k0 = 0; k0 < Cch; k0 += 64) {
#pragma unroll
    for (int p = 0; p < 2; p++) {
      int idx = tid + p * 512, row = idx >> 3, seg = idx & 7;
      *(u16x8*)&Ah[0][row][seg * 8] = *(const u16x8*)&Ahi[(size_t)(brow + row) * Cch + k0 + seg * 8];
      *(u16x8*)&Ah[1][row][seg * 8] = *(const u16x8*)&Alo[(size_t)(brow + row) * Cch + k0 + seg * 8];
    }
    {
      int row = tid >> 3, seg = tid & 7;
      *(u16x8*)&Bs[0][row][seg * 8] = *(const u16x8*)&Bhi[(size_t)(bcol + row) * Cch + k0 + seg * 8];
      *(u16x8*)&Bs[1][row][seg * 8] = *(const u16x8*)&Blo[(size_t)(bcol + row) * Cch + k0 + seg * 8];
    }
    __syncthreads();
#pragma unroll
    for (int ks = 0; ks < 2; ks++) {
      s16x8 ah[2], al[2], bh[2], bl[2];
#pragma unroll
      for (int ti = 0; ti < 2; ti++) {
        ah[ti] = *(const s16x8*)&Ah[0][wr * 32 + ti * 16 + lr][ks * 32 + e * 8];
        al[ti] = *(const s16x8*)&Ah[1][wr * 32 + ti * 16 + lr][ks * 32 + e * 8];
      }
#pragma unroll
      for (int tj = 0; tj < 2; tj++) {
        bh[tj] = *(const s16x8*)&Bs[0][wc * 32 + tj * 16 + lr][ks * 32 + e * 8];
        bl[tj] = *(const s16x8*)&Bs[1][wc * 32 + tj * 16 + lr][ks * 32 + e * 8];
      }
#pragma unroll
      for (int ti = 0; ti < 2; ti++)
#pragma unroll
        for (int tj = 0; tj < 2; tj++) {
          acc[ti][tj] = __builtin_amdgcn_mfma_f32_16x16x32_bf16(ah[ti], bh[tj], acc[ti][tj], 0, 0, 0);
          acc[ti][tj] = __builtin_amdgcn_mfma_f32_16x16x32_bf16(ah[ti], bl[tj], acc[ti][tj], 0, 0, 0);
          acc[ti][tj] = __builtin_amdgcn_mfma_f32_16x16x32_bf16(al[ti], bh[tj], acc[ti][tj], 0, 0, 0);
        }
    }
    __syncthreads();
  }
#pragma unroll
  for (int ti = 0; ti < 2; ti++)
#pragma unroll
    for (int tj = 0; tj < 2; tj++) {
      int col = bcol + wc * 32 + tj * 16 + lr;
      float bi = bias[col];
#pragma unroll
      for (int r = 0; r < 4; r++) {
        int row = brow + wr * 32 + ti * 16 + e * 4 + r;
        Out[(size_t)row * Cch + col] = acc[ti][tj][r] + bi;
      }
    }
}

// ---------- V normalize + transpose via LDS: Vf[token][C] f32 -> Vt[bh*64+d][t] bf16 ----------
__global__ __launch_bounds__(256) void vnormt_k(const float* __restrict__ Vf,
                                                unsigned short* __restrict__ Vt) {
  __shared__ unsigned short T[64][72];  // [d][token] bf16
  const int tid = threadIdx.x;
  const int t0 = blockIdx.x * 64;
  const int h = blockIdx.y;
  const int tok = tid >> 2;
  const int q = tid & 3;
  const float* src = Vf + (size_t)(t0 + tok) * Cch + h * 64 + q * 16;
  f32x4 v[4];
  float ss = 0.f;
#pragma unroll
  for (int i = 0; i < 4; i++) {
    v[i] = *(const f32x4*)(src + i * 4);
#pragma unroll
    for (int c = 0; c < 4; c++) ss += v[i][c] * v[i][c];
  }
  ss += __shfl_xor(ss, 1);
  ss += __shfl_xor(ss, 2);
  float inv = 1.0f / fmaxf(sqrtf(ss), 1e-12f);
#pragma unroll
  for (int i = 0; i < 4; i++)
#pragma unroll
    for (int c = 0; c < 4; c++)
      T[q * 16 + i * 4 + c][tok] = f2bf(v[i][c] * inv);
  __syncthreads();
  const int d = tid >> 2, s2 = (tid & 3) * 2;
  const int b = t0 >> 11;
  size_t base = ((size_t)((b * Hc + h) * 64 + d)) * Tc + (t0 & 2047);
  *(u16x8*)(Vt + base + s2 * 8)     = *(const u16x8*)&T[d][s2 * 8];
  *(u16x8*)(Vt + base + s2 * 8 + 8) = *(const u16x8*)&T[d][s2 * 8 + 8];
}

// ---------- S = (Q K^T)/8 into causal-compact triangular storage ----------
__global__ __launch_bounds__(512) void sqk_k(const unsigned short* __restrict__ Qp,
    const unsigned short* __restrict__ Kp, float* __restrict__ S, int bh0) {
  __shared__ unsigned short Qs[128][72], Ks[128][72];
  int rt, ct;
  {
    int i = blockIdx.x;
    int r = (int)((sqrtf(8.f * i + 1.f) - 1.f) * 0.5f);
    while ((r + 1) * (r + 2) / 2 <= i) r++;
    while (r * (r + 1) / 2 > i) r--;
    rt = r; ct = i - r * (r + 1) / 2;
  }
  const int bh = bh0 + blockIdx.y, b = bh >> 3, h = bh & 7;
  const int tid = threadIdx.x, w = tid >> 6, lane = tid & 63, e = lane >> 4, lr = lane & 15;
#pragma unroll
  for (int p = 0; p < 2; p++) {
    int idx = tid + p * 512, row = idx >> 3, seg = idx & 7;
    *(u16x8*)&Qs[row][seg * 8] = *(const u16x8*)&Qp[((size_t)(b * Tc + rt * 128 + row)) * Cch + h * 64 + seg * 8];
    *(u16x8*)&Ks[row][seg * 8] = *(const u16x8*)&Kp[((size_t)(b * Tc + ct * 128 + row)) * Cch + h * 64 + seg * 8];
  }
  __syncthreads();
  f32x4 acc[8] = {};
  s16x8 a[2];
#pragma unroll
  for (int ks = 0; ks < 2; ks++) a[ks] = *(const s16x8*)&Qs[w * 16 + lr][ks * 32 + e * 8];
#pragma unroll
  for (int tj = 0; tj < 8; tj++) {
#pragma unroll
    for (int ks = 0; ks < 2; ks++) {
      s16x8 bb = *(const s16x8*)&Ks[tj * 16 + lr][ks * 32 + e * 8];
      acc[tj] = __builtin_amdgcn_mfma_f32_16x16x32_bf16(a[ks], bb, acc[tj], 0, 0, 0);
    }
  }
  float* Srow0 = S + (size_t)(bh - bh0) * TRI_FLOATS + (size_t)tri_i(rt) * 16384;
  const int stride = (rt + 1) * 128;
#pragma unroll
  for (int tj = 0; tj < 8; tj++)
#pragma unroll
    for (int r = 0; r < 4; r++) {
      int row = w * 16 + e * 4 + r;
      Srow0[(size_t)row * stride + ct * 128 + tj * 16 + lr] = acc[tj][r] * 0.125f;
    }
}

// ---------- exact top-64 + softmax; guarded radix with [mM,mmx] prefix skip ----------
// T (64th largest) obeys mM <= T <= mmx where mM = wave-min of per-lane maxima
// (64 distinct elements >= mM). Start search at first differing bit. Guards,
// early-exit, min-refine, write phase identical to the validated R13 form.
__global__ __launch_bounds__(512, 4) void sel_k(float* __restrict__ S) {
  int bidr = (int)gridDim.x - 1 - (int)blockIdx.x;   // long rows dispatch first
  int wid = bidr * 8 + (threadIdx.x >> 6);
  int lane = threadIdx.x & 63;
  int bhl = wid >> 11, t = wid & 2047;
  int rt = t >> 7, lrow = t & 127;
  int stride = (rt + 1) * 128;
  float* row = S + (size_t)bhl * TRI_FLOATS + (size_t)tri_i(rt) * 16384 + (size_t)lrow * stride;
  unsigned su[32];
#pragma unroll
  for (int c = 0; c < 8; c++) {
    if (c * 256 < stride) {
      int j0 = c * 256 + lane * 4;
      f32x4 v;
      if (j0 < stride) v = *(const f32x4*)(row + j0);
      else { v[0] = v[1] = v[2] = v[3] = -INFINITY; }
#pragma unroll
      for (int cc = 0; cc < 4; cc++) {
        float x = (j0 + cc <= t) ? v[cc] : -INFINITY;
        unsigned u = __float_as_uint(x);
        su[c * 4 + cc] = (u & 0x80000000u) ? ~u : (u | 0x80000000u);
      }
    } else {
#pragma unroll
      for (int cc = 0; cc < 4; cc++) su[c * 4 + cc] = 0x007FFFFFu;  // map(-inf)
    }
  }
  // per-lane max over active chunks -> wave max (mmx) and wave min-of-lane-max (mM)
  unsigned lmax = 0;
#pragma unroll
  for (int c = 0; c < 8; c++)
    if (c * 256 < stride)
#pragma unroll
      for (int q = 0; q < 4; q++) lmax = lmax > su[c * 4 + q] ? lmax : su[c * 4 + q];
  unsigned mmx = lmax, mM = lmax;
#pragma unroll
  for (int o = 32; o; o >>= 1) {
    unsigned a = (unsigned)__shfl_xor((int)mmx, o); mmx = mmx > a ? mmx : a;
    unsigned bmin = (unsigned)__shfl_xor((int)mM, o); mM = mM < bmin ? mM : bmin;
  }
  unsigned lo;
  unsigned xr = mM ^ mmx;
  if (xr == 0) {
    lo = mM;  // >=64 elements equal the max (one per lane)
  } else {
    int pbit = 31 - __builtin_clz(xr);
    lo = mM & ~((2u << pbit) - 1u);  // common prefix of [mM, mmx]
#pragma unroll 1
    for (int bit = pbit; bit >= 0; bit--) {
      unsigned cand = lo | (1u << bit);
      int cnt = 0;
#pragma unroll
      for (int c = 0; c < 8; c++)
        if (c * 256 < stride)
#pragma unroll
          for (int q = 0; q < 4; q++)
            cnt += (int)__popcll(__ballot(su[c * 4 + q] >= cand));
      if (cnt >= 64) {
        lo = cand;
        if (cnt == 64) {
          unsigned mn = 0xFFFFFFFFu;
#pragma unroll
          for (int c = 0; c < 8; c++)
            if (c * 256 < stride)
#pragma unroll
              for (int q = 0; q < 4; q++) { unsigned x = (su[c * 4 + q] >= cand) ? su[c * 4 + q] : 0xFFFFFFFFu; mn = mn < x ? mn : x; }
#pragma unroll
          for (int o = 32; o; o >>= 1) { unsigned x = (unsigned)__shfl_xor((int)mn, o); mn = mn < x ? mn : x; }
          lo = mn;
          break;
        }
      }
    }
  }
  float m = su2f(mmx);
  float sum = 0.f;
#pragma unroll
  for (int c = 0; c < 8; c++)
    if (c * 256 < stride)
#pragma unroll
      for (int q = 0; q < 4; q++) {
        float v = su2f(su[c * 4 + q]);
        float wv = (su[c * 4 + q] >= lo) ? __expf(v - m) : 0.f;  // exp(-inf)=0
        su[c * 4 + q] = __float_as_uint(wv);
        sum += wv;
      }
  sum = wave_sum_f(sum);
  float inv = 1.f / sum;
  unsigned short* prow = (unsigned short*)row;
#pragma unroll
  for (int c = 0; c < 8; c++) {
    if (c * 256 < stride) {
      int j0 = c * 256 + lane * 4;
      if (j0 < stride) {
        u16x4 pk;
#pragma unroll
        for (int cc = 0; cc < 4; cc++) pk[cc] = f2bf(__uint_as_float(su[c * 4 + cc]) * inv);
        *(u16x4*)(prow + j0) = pk;
      }
    }
  }
}

// ---------- Y = P @ V^T: 64-row blocks, LPT (big rt first) — R13-validated form ----------
__global__ __launch_bounds__(512) void pv_k(const float* __restrict__ S,
    const unsigned short* __restrict__ Vt,
    unsigned short* __restrict__ Yhi, unsigned short* __restrict__ Ylo, int bh0) {
  __shared__ unsigned short Ps[64][136];
  __shared__ unsigned short Vs[64][136];
  const int x = blockIdx.x;                    // 0..2*NRT-1
  const int rt = NRT - 1 - (x >> 1);           // big rt dispatched first
  const int half = x & 1;
  const int bh = bh0 + blockIdx.y, b = bh >> 3, h = bh & 7;
  const int tid = threadIdx.x, w = tid >> 6, lane = tid & 63, e = lane >> 4, lr = lane & 15;
  const int stride = (rt + 1) * 128;
  const int rbase = half * 64;                 // local row base within the 128-row tile
  const float* Srow0 = S + (size_t)(bh - bh0) * TRI_FLOATS + (size_t)tri_i(rt) * 16384;
  const int rg = w & 3, dh = w >> 2;           // row-group (16 rows), d-half (32 cols)
  f32x4 acc[2] = {};
  for (int kt = 0; kt <= rt; kt++) {
#pragma unroll
    for (int p = 0; p < 2; p++) {
      int idx = tid + p * 512, pr = idx >> 4, seg = idx & 15;
      const unsigned short* src =
          (const unsigned short*)(Srow0 + (size_t)(rbase + pr) * stride) + kt * 128 + seg * 8;
      *(u16x8*)&Ps[pr][seg * 8] = *(const u16x8*)src;
      *(u16x8*)&Vs[pr][seg * 8] = *(const u16x8*)&Vt[((size_t)(bh * 64 + pr)) * Tc + kt * 128 + seg * 8];
    }
    __syncthreads();
#pragma unroll
    for (int ks = 0; ks < 4; ks++) {
      s16x8 a = *(const s16x8*)&Ps[rg * 16 + lr][ks * 32 + e * 8];
#pragma unroll
      for (int tj = 0; tj < 2; tj++) {
        s16x8 bb = *(const s16x8*)&Vs[dh * 32 + tj * 16 + lr][ks * 32 + e * 8];
        acc[tj] = __builtin_amdgcn_mfma_f32_16x16x32_bf16(a, bb, acc[tj], 0, 0, 0);
      }
    }
    __syncthreads();
  }
#pragma unroll
  for (int tj = 0; tj < 2; tj++)
#pragma unroll
    for (int r = 0; r < 4; r++) {
      int row = rt * 128 + rbase + rg * 16 + e * 4 + r;
      size_t g = ((size_t)(b * Tc + row)) * Cch + h * 64 + dh * 32 + tj * 16 + lr;
      float y = acc[tj][r];
      unsigned short hh = f2bf(y);
      Yhi[g] = hh;
      Ylo[g] = f2bf(y - bf2f(hh));
    }
}

extern "C" void kernel_launch(void* const* d_in, const int* in_sizes, int n_in,
                              void* d_out, int out_size, void* d_ws, size_t ws_size,
                              hipStream_t stream) {
  const float* q  = (const float*)d_in[0];
  // d_in[1] = tgt_mask: pure causal tril, handled analytically
  const float* Wq = (const float*)d_in[2];
  const float* bq = (const float*)d_in[3];
  const float* Wk = (const float*)d_in[4];
  const float* bk = (const float*)d_in[5];
  const float* Wv = (const float*)d_in[6];
  const float* bv = (const float*)d_in[7];
  const float* Wp = (const float*)d_in[8];
  const float* bp = (const float*)d_in[9];
  float* out = (float*)d_out;
  char* ws = (char*)d_ws;
  constexpr size_t MB = 1u << 20;

  unsigned short* Yhi = (unsigned short*)(ws + 0 * MB);   // 4 MB
  unsigned short* Ylo = (unsigned short*)(ws + 4 * MB);   // 4 MB
  unsigned short* Qp  = (unsigned short*)(ws + 8 * MB);   // 4 MB
  unsigned short* Kp  = (unsigned short*)(ws + 12 * MB);  // 4 MB
  unsigned short* Vt  = (unsigned short*)(ws + 16 * MB);  // 4 MB
  unsigned short* wsp = (unsigned short*)(ws + 20 * MB);  // 8 x 512 KB weight splits
  float* Sb = (float*)(ws + 24 * MB);                     // S/P region (chunked)
  float* Vf = (float*)(ws + 24 * MB);                     // overlays S (consumed first)

  int nbh = NBH;
  while (nbh > 1 && 24 * MB + TRI_FLOATS * 4 * (size_t)nbh > ws_size) nbh >>= 1;

  splitT4_k<<<dim3(8, 8, 4), 256, 0, stream>>>(Wq, Wk, Wv, Wp, wsp);

  gemm3w_qkv_k<<<dim3(Cch / 64, BT / 128, 3), 512, 0, stream>>>(
      q, wsp, bq, bk, bv, Qp, Kp, Vf);
  vnormt_k<<<dim3(BT / 64, Hc), 256, 0, stream>>>(Vf, Vt);

  for (int c = 0; c < NBH / nbh; c++) {
    int bh0 = c * nbh;
    sqk_k<<<dim3(NTRI, nbh), 512, 0, stream>>>(Qp, Kp, Sb, bh0);
    sel_k<<<nbh * 256, 512, 0, stream>>>(Sb);
    pv_k<<<dim3(2 * NRT, nbh), 512, 0, stream>>>(Sb, Vt, Yhi, Ylo, bh0);
  }

  gemm3w_out_k<<<dim3(Cch / 64, BT / 128), 512, 0, stream>>>(
      Yhi, Ylo, wsp + (size_t)6 * 262144, wsp + (size_t)7 * 262144, bp, out);
}

// Round 17
// 198.004 us; speedup vs baseline: 1.0988x; 1.0259x over previous
//
#include <hip/hip_runtime.h>
#include <cstdint>
#include <math.h>

static constexpr int Bc = 2, Tc = 2048, Cch = 512, Hc = 8;
static constexpr int BT = Bc * Tc;          // 4096
static constexpr int NBH = Bc * Hc;         // 16
static constexpr int NRT = Tc / 128;        // 16 row-tiles per (b,h)
static constexpr int NTRI = NRT * (NRT + 1) / 2;  // 136 causal blocks
static constexpr size_t TRI_FLOATS = (size_t)NTRI * 16384;  // f32 per (b,h)

typedef float f32x4 __attribute__((ext_vector_type(4)));
typedef short s16x8 __attribute__((ext_vector_type(8)));
typedef unsigned short u16x8 __attribute__((ext_vector_type(8)));
typedef unsigned short u16x4 __attribute__((ext_vector_type(4)));

__device__ __host__ inline constexpr int tri_i(int r) { return r * (r + 1) / 2; }

__device__ inline float wave_sum_f(float x) {
#pragma unroll
  for (int o = 32; o; o >>= 1) x += __shfl_xor(x, o);
  return x;
}
__device__ inline unsigned short f2bf(float x) {  // RNE f32->bf16 (finite)
  unsigned u = __float_as_uint(x);
  return (unsigned short)((u + 0x7FFFu + ((u >> 16) & 1u)) >> 16);
}
__device__ inline float bf2f(unsigned short h) { return __uint_as_float(((unsigned)h) << 16); }
__device__ inline float su2f(unsigned s) {  // inverse order-preserving map
  unsigned u = (s & 0x80000000u) ? (s ^ 0x80000000u) : ~s;
  return __uint_as_float(u);
}

// ---------- split + transpose all 4 weights: W[k][n] f32 -> WT[n][k] bf16 hi/lo ----------
__global__ __launch_bounds__(256) void splitT4_k(const float* __restrict__ Wq,
    const float* __restrict__ Wk, const float* __restrict__ Wv,
    const float* __restrict__ Wp, unsigned short* __restrict__ wsp) {
  const int z = blockIdx.z;
  const float* W = (z == 0) ? Wq : (z == 1) ? Wk : (z == 2) ? Wv : Wp;
  unsigned short* hiT = wsp + (size_t)z * 524288;
  unsigned short* loT = hiT + 262144;
  __shared__ float t[64][65];
  const int tid = threadIdx.x;
  const int k0 = blockIdx.x * 64, n0 = blockIdx.y * 64;
#pragma unroll
  for (int p = 0; p < 4; p++) {
    int idx = tid + p * 256, kk = idx >> 4, n4 = idx & 15;
    f32x4 v = *(const f32x4*)&W[(size_t)(k0 + kk) * Cch + n0 + n4 * 4];
    t[kk][n4 * 4 + 0] = v[0]; t[kk][n4 * 4 + 1] = v[1];
    t[kk][n4 * 4 + 2] = v[2]; t[kk][n4 * 4 + 3] = v[3];
  }
  __syncthreads();
  {
    int n = tid >> 2, ks = tid & 3;
    u16x8 h0, h1, l0, l1;
#pragma unroll
    for (int kk = 0; kk < 8; kk++) {
      float x = t[ks * 16 + kk][n];
      unsigned short hh = f2bf(x);
      h0[kk] = hh; l0[kk] = f2bf(x - bf2f(hh));
      float y = t[ks * 16 + 8 + kk][n];
      unsigned short hy = f2bf(y);
      h1[kk] = hy; l1[kk] = f2bf(y - bf2f(hy));
    }
    size_t base = (size_t)(n0 + n) * Cch + k0 + ks * 16;
    *(u16x8*)(hiT + base) = h0; *(u16x8*)(hiT + base + 8) = h1;
    *(u16x8*)(loT + base) = l0; *(u16x8*)(loT + base + 8) = l1;
  }
}

// ---------- merged Q/K/V projection; z==2 fuses V-norm + transpose (writes Vt) ----------
__global__ __launch_bounds__(512) void gemm3w_qkv_k(
    const float* __restrict__ Aq, const unsigned short* __restrict__ wsp,
    const float* __restrict__ bq, const float* __restrict__ bk, const float* __restrict__ bv,
    unsigned short* __restrict__ Qp, unsigned short* __restrict__ Kp,
    unsigned short* __restrict__ Vt) {
  const int z = blockIdx.z;
  const unsigned short* Bhi = wsp + (size_t)z * 524288;
  const unsigned short* Blo = Bhi + 262144;
  const float* bias = (z == 0) ? bq : (z == 1) ? bk : bv;
  __shared__ unsigned short Ah[2][128][72];
  __shared__ unsigned short Bs[2][64][72];
  const int tid = threadIdx.x;
  const int w = tid >> 6, lane = tid & 63, e = lane >> 4, lr = lane & 15;
  const int wr = w >> 1, wc = w & 1;                 // 4x2 wave grid
  const int brow = blockIdx.y * 128, bcol = blockIdx.x * 64;
  f32x4 acc[2][2] = {};
  for (int k0 = 0; k0 < Cch; k0 += 64) {
#pragma unroll
    for (int p = 0; p < 4; p++) {
      int idx = tid + p * 512, row = idx >> 4, seg = idx & 15;  // 128 rows x 16 f32x4 segs
      f32x4 v = *(const f32x4*)&Aq[(size_t)(brow + row) * Cch + k0 + seg * 4];
      u16x4 hv, lv;
#pragma unroll
      for (int c = 0; c < 4; c++) {
        unsigned short hh = f2bf(v[c]);
        hv[c] = hh;
        lv[c] = f2bf(v[c] - bf2f(hh));
      }
      *(u16x4*)&Ah[0][row][seg * 4] = hv;
      *(u16x4*)&Ah[1][row][seg * 4] = lv;
    }
    {
      int row = tid >> 3, seg = tid & 7;
      *(u16x8*)&Bs[0][row][seg * 8] = *(const u16x8*)&Bhi[(size_t)(bcol + row) * Cch + k0 + seg * 8];
      *(u16x8*)&Bs[1][row][seg * 8] = *(const u16x8*)&Blo[(size_t)(bcol + row) * Cch + k0 + seg * 8];
    }
    __syncthreads();
#pragma unroll
    for (int ks = 0; ks < 2; ks++) {
      s16x8 ah[2], al[2], bh[2], bl[2];
#pragma unroll
      for (int ti = 0; ti < 2; ti++) {
        ah[ti] = *(const s16x8*)&Ah[0][wr * 32 + ti * 16 + lr][ks * 32 + e * 8];
        al[ti] = *(const s16x8*)&Ah[1][wr * 32 + ti * 16 + lr][ks * 32 + e * 8];
      }
#pragma unroll
      for (int tj = 0; tj < 2; tj++) {
        bh[tj] = *(const s16x8*)&Bs[0][wc * 32 + tj * 16 + lr][ks * 32 + e * 8];
        bl[tj] = *(const s16x8*)&Bs[1][wc * 32 + tj * 16 + lr][ks * 32 + e * 8];
      }
#pragma unroll
      for (int ti = 0; ti < 2; ti++)
#pragma unroll
        for (int tj = 0; tj < 2; tj++) {
          acc[ti][tj] = __builtin_amdgcn_mfma_f32_16x16x32_bf16(ah[ti], bh[tj], acc[ti][tj], 0, 0, 0);
          acc[ti][tj] = __builtin_amdgcn_mfma_f32_16x16x32_bf16(ah[ti], bl[tj], acc[ti][tj], 0, 0, 0);
          acc[ti][tj] = __builtin_amdgcn_mfma_f32_16x16x32_bf16(al[ti], bh[tj], acc[ti][tj], 0, 0, 0);
        }
    }
    __syncthreads();
  }
  if (z != 2) {
#pragma unroll
    for (int ti = 0; ti < 2; ti++)
#pragma unroll
      for (int tj = 0; tj < 2; tj++) {
        int col = bcol + wc * 32 + tj * 16 + lr;
        float bi = bias[col];
#pragma unroll
        for (int r = 0; r < 4; r++) {
          int row = brow + wr * 32 + ti * 16 + e * 4 + r;
          float v = acc[ti][tj][r] + bi;
          size_t g = (size_t)row * Cch + col;
          if (z == 0) Qp[g] = f2bf(v);
          else Kp[g] = f2bf(v);
        }
      }
  } else {
    // V path: stage f32 into reused LDS (fits in Ah: 128*68*4 = 34816 <= 36864)
    float* vlds = (float*)&Ah[0][0][0];
#pragma unroll
    for (int ti = 0; ti < 2; ti++)
#pragma unroll
      for (int tj = 0; tj < 2; tj++) {
        int cl = wc * 32 + tj * 16 + lr;      // local col (d) 0..63
        float bi = bias[bcol + cl];
#pragma unroll
        for (int r = 0; r < 4; r++) {
          int rl = wr * 32 + ti * 16 + e * 4 + r;  // local row (token) 0..127
          vlds[rl * 68 + cl] = acc[ti][tj][r] + bi;
        }
      }
    __syncthreads();
    // per-token norm: 4 threads per row, same grouping/order as old vnormt_k
    {
      int row = tid >> 2, qq = tid & 3;
      float vv[16];
      float ss = 0.f;
#pragma unroll
      for (int i = 0; i < 16; i++) {
        vv[i] = vlds[row * 68 + qq * 16 + i];
        ss += vv[i] * vv[i];
      }
      ss += __shfl_xor(ss, 1);
      ss += __shfl_xor(ss, 2);
      float invn = 1.0f / fmaxf(sqrtf(ss), 1e-12f);
#pragma unroll
      for (int i = 0; i < 16; i++) vlds[row * 68 + qq * 16 + i] = vv[i] * invn;
    }
    __syncthreads();
    // transposed coalesced write: Vt[(bh*64+d)*Tc + t]
    {
      int d = tid >> 3, s8 = tid & 7;       // 64 d x 8 segments of 16 tokens
      int b2 = brow >> 11;
      size_t base = ((size_t)((b2 * Hc + blockIdx.x) * 64 + d)) * Tc + (brow & 2047) + s8 * 16;
      u16x8 o0, o1;
#pragma unroll
      for (int i = 0; i < 8; i++) o0[i] = f2bf(vlds[(s8 * 16 + i) * 68 + d]);
#pragma unroll
      for (int i = 0; i < 8; i++) o1[i] = f2bf(vlds[(s8 * 16 + 8 + i) * 68 + d]);
      *(u16x8*)(Vt + base) = o0;
      *(u16x8*)(Vt + base + 8) = o1;
    }
  }
}

// ---------- output projection: A pre-split (Yhi/Ylo), f32 out ----------
__global__ __launch_bounds__(512) void gemm3w_out_k(
    const unsigned short* __restrict__ Ahi, const unsigned short* __restrict__ Alo,
    const unsigned short* __restrict__ Bhi, const unsigned short* __restrict__ Blo,
    const float* __restrict__ bias, float* __restrict__ Out) {
  __shared__ unsigned short Ah[2][128][72];
  __shared__ unsigned short Bs[2][64][72];
  const int tid = threadIdx.x;
  const int w = tid >> 6, lane = tid & 63, e = lane >> 4, lr = lane & 15;
  const int wr = w >> 1, wc = w & 1;
  const int brow = blockIdx.y * 128, bcol = blockIdx.x * 64;
  f32x4 acc[2][2] = {};
  for (int k0 = 0; k0 < Cch; k0 += 64) {
#pragma unroll
    for (int p = 0; p < 2; p++) {
      int idx = tid + p * 512, row = idx >> 3, seg = idx & 7;
      *(u16x8*)&Ah[0][row][seg * 8] = *(const u16x8*)&Ahi[(size_t)(brow + row) * Cch + k0 + seg * 8];
      *(u16x8*)&Ah[1][row][seg * 8] = *(const u16x8*)&Alo[(size_t)(brow + row) * Cch + k0 + seg * 8];
    }
    {
      int row = tid >> 3, seg = tid & 7;
      *(u16x8*)&Bs[0][row][seg * 8] = *(const u16x8*)&Bhi[(size_t)(bcol + row) * Cch + k0 + seg * 8];
      *(u16x8*)&Bs[1][row][seg * 8] = *(const u16x8*)&Blo[(size_t)(bcol + row) * Cch + k0 + seg * 8];
    }
    __syncthreads();
#pragma unroll
    for (int ks = 0; ks < 2; ks++) {
      s16x8 ah[2], al[2], bh[2], bl[2];
#pragma unroll
      for (int ti = 0; ti < 2; ti++) {
        ah[ti] = *(const s16x8*)&Ah[0][wr * 32 + ti * 16 + lr][ks * 32 + e * 8];
        al[ti] = *(const s16x8*)&Ah[1][wr * 32 + ti * 16 + lr][ks * 32 + e * 8];
      }
#pragma unroll
      for (int tj = 0; tj < 2; tj++) {
        bh[tj] = *(const s16x8*)&Bs[0][wc * 32 + tj * 16 + lr][ks * 32 + e * 8];
        bl[tj] = *(const s16x8*)&Bs[1][wc * 32 + tj * 16 + lr][ks * 32 + e * 8];
      }
#pragma unroll
      for (int ti = 0; ti < 2; ti++)
#pragma unroll
        for (int tj = 0; tj < 2; tj++) {
          acc[ti][tj] = __builtin_amdgcn_mfma_f32_16x16x32_bf16(ah[ti], bh[tj], acc[ti][tj], 0, 0, 0);
          acc[ti][tj] = __builtin_amdgcn_mfma_f32_16x16x32_bf16(ah[ti], bl[tj], acc[ti][tj], 0, 0, 0);
          acc[ti][tj] = __builtin_amdgcn_mfma_f32_16x16x32_bf16(al[ti], bh[tj], acc[ti][tj], 0, 0, 0);
        }
    }
    __syncthreads();
  }
#pragma unroll
  for (int ti = 0; ti < 2; ti++)
#pragma unroll
    for (int tj = 0; tj < 2; tj++) {
      int col = bcol + wc * 32 + tj * 16 + lr;
      float bi = bias[col];
#pragma unroll
      for (int r = 0; r < 4; r++) {
        int row = brow + wr * 32 + ti * 16 + e * 4 + r;
        Out[(size_t)row * Cch + col] = acc[ti][tj][r] + bi;
      }
    }
}

// ---------- S = (Q K^T)/8 into causal-compact storage; diagonal tiles pre-masked ----------
__global__ __launch_bounds__(512) void sqk_k(const unsigned short* __restrict__ Qp,
    const unsigned short* __restrict__ Kp, float* __restrict__ S, int bh0) {
  __shared__ unsigned short Qs[128][72], Ks[128][72];
  int rt, ct;
  {
    int i = blockIdx.x;
    int r = (int)((sqrtf(8.f * i + 1.f) - 1.f) * 0.5f);
    while ((r + 1) * (r + 2) / 2 <= i) r++;
    while (r * (r + 1) / 2 > i) r--;
    rt = r; ct = i - r * (r + 1) / 2;
  }
  const int bh = bh0 + blockIdx.y, b = bh >> 3, h = bh & 7;
  const int tid = threadIdx.x, w = tid >> 6, lane = tid & 63, e = lane >> 4, lr = lane & 15;
#pragma unroll
  for (int p = 0; p < 2; p++) {
    int idx = tid + p * 512, row = idx >> 3, seg = idx & 7;
    *(u16x8*)&Qs[row][seg * 8] = *(const u16x8*)&Qp[((size_t)(b * Tc + rt * 128 + row)) * Cch + h * 64 + seg * 8];
    *(u16x8*)&Ks[row][seg * 8] = *(const u16x8*)&Kp[((size_t)(b * Tc + ct * 128 + row)) * Cch + h * 64 + seg * 8];
  }
  __syncthreads();
  f32x4 acc[8] = {};
  s16x8 a[2];
#pragma unroll
  for (int ks = 0; ks < 2; ks++) a[ks] = *(const s16x8*)&Qs[w * 16 + lr][ks * 32 + e * 8];
#pragma unroll
  for (int tj = 0; tj < 8; tj++) {
#pragma unroll
    for (int ks = 0; ks < 2; ks++) {
      s16x8 bb = *(const s16x8*)&Ks[tj * 16 + lr][ks * 32 + e * 8];
      acc[tj] = __builtin_amdgcn_mfma_f32_16x16x32_bf16(a[ks], bb, acc[tj], 0, 0, 0);
    }
  }
  float* Srow0 = S + (size_t)(bh - bh0) * TRI_FLOATS + (size_t)tri_i(rt) * 16384;
  const int stride = (rt + 1) * 128;
  if (ct == rt) {  // diagonal tile: mask j > t at write time (uniform branch)
#pragma unroll
    for (int tj = 0; tj < 8; tj++)
#pragma unroll
      for (int r = 0; r < 4; r++) {
        int row = w * 16 + e * 4 + r;
        float val = (tj * 16 + lr > row) ? -INFINITY : acc[tj][r] * 0.125f;
        Srow0[(size_t)row * stride + ct * 128 + tj * 16 + lr] = val;
      }
  } else {
#pragma unroll
    for (int tj = 0; tj < 8; tj++)
#pragma unroll
      for (int r = 0; r < 4; r++) {
        int row = w * 16 + e * 4 + r;
        Srow0[(size_t)row * stride + ct * 128 + tj * 16 + lr] = acc[tj][r] * 0.125f;
      }
  }
}

// ---------- exact top-64 + softmax; causal mask pre-applied by sqk ----------
// guarded radix + [mM,mmx] prefix skip (R16-validated); writes normalized P bf16 in-place
__global__ __launch_bounds__(512, 4) void sel_k(float* __restrict__ S) {
  int bidr = (int)gridDim.x - 1 - (int)blockIdx.x;   // long rows dispatch first
  int wid = bidr * 8 + (threadIdx.x >> 6);
  int lane = threadIdx.x & 63;
  int bhl = wid >> 11, t = wid & 2047;
  int rt = t >> 7, lrow = t & 127;
  int stride = (rt + 1) * 128;
  float* row = S + (size_t)bhl * TRI_FLOATS + (size_t)tri_i(rt) * 16384 + (size_t)lrow * stride;
  unsigned su[32];
#pragma unroll
  for (int c = 0; c < 8; c++) {
    if (c * 256 < stride) {
      int j0 = c * 256 + lane * 4;
      f32x4 v;
      if (j0 < stride) v = *(const f32x4*)(row + j0);
      else { v[0] = v[1] = v[2] = v[3] = -INFINITY; }
#pragma unroll
      for (int cc = 0; cc < 4; cc++) {
        unsigned u = __float_as_uint(v[cc]);   // causal -inf already in S
        su[c * 4 + cc] = (u & 0x80000000u) ? ~u : (u | 0x80000000u);
      }
    } else {
#pragma unroll
      for (int cc = 0; cc < 4; cc++) su[c * 4 + cc] = 0x007FFFFFu;  // map(-inf)
    }
  }
  // per-lane max over active chunks -> wave max (mmx) and wave min-of-lane-max (mM)
  unsigned lmax = 0;
#pragma unroll
  for (int c = 0; c < 8; c++)
    if (c * 256 < stride)
#pragma unroll
      for (int q = 0; q < 4; q++) lmax = lmax > su[c * 4 + q] ? lmax : su[c * 4 + q];
  unsigned mmx = lmax, mM = lmax;
#pragma unroll
  for (int o = 32; o; o >>= 1) {
    unsigned a = (unsigned)__shfl_xor((int)mmx, o); mmx = mmx > a ? mmx : a;
    unsigned bmin = (unsigned)__shfl_xor((int)mM, o); mM = mM < bmin ? mM : bmin;
  }
  unsigned lo;
  unsigned xr = mM ^ mmx;
  if (xr == 0) {
    lo = mM;  // >=64 elements equal the max (one per lane)
  } else {
    int pbit = 31 - __builtin_clz(xr);
    lo = mM & ~((2u << pbit) - 1u);  // common prefix of [mM, mmx]
#pragma unroll 1
    for (int bit = pbit; bit >= 0; bit--) {
      unsigned cand = lo | (1u << bit);
      int cnt = 0;
#pragma unroll
      for (int c = 0; c < 8; c++)
        if (c * 256 < stride)
#pragma unroll
          for (int q = 0; q < 4; q++)
            cnt += (int)__popcll(__ballot(su[c * 4 + q] >= cand));
      if (cnt >= 64) {
        lo = cand;
        if (cnt == 64) {
          unsigned mn = 0xFFFFFFFFu;
#pragma unroll
          for (int c = 0; c < 8; c++)
            if (c * 256 < stride)
#pragma unroll
              for (int q = 0; q < 4; q++) { unsigned x = (su[c * 4 + q] >= cand) ? su[c * 4 + q] : 0xFFFFFFFFu; mn = mn < x ? mn : x; }
#pragma unroll
          for (int o = 32; o; o >>= 1) { unsigned x = (unsigned)__shfl_xor((int)mn, o); mn = mn < x ? mn : x; }
          lo = mn;
          break;
        }
      }
    }
  }
  float m = su2f(mmx);
  float sum = 0.f;
#pragma unroll
  for (int c = 0; c < 8; c++)
    if (c * 256 < stride)
#pragma unroll
      for (int q = 0; q < 4; q++) {
        float v = su2f(su[c * 4 + q]);
        float wv = (su[c * 4 + q] >= lo) ? __expf(v - m) : 0.f;  // exp(-inf)=0
        su[c * 4 + q] = __float_as_uint(wv);
        sum += wv;
      }
  sum = wave_sum_f(sum);
  float inv = 1.f / sum;
  unsigned short* prow = (unsigned short*)row;
#pragma unroll
  for (int c = 0; c < 8; c++) {
    if (c * 256 < stride) {
      int j0 = c * 256 + lane * 4;
      if (j0 < stride) {
        u16x4 pk;
#pragma unroll
        for (int cc = 0; cc < 4; cc++) pk[cc] = f2bf(__uint_as_float(su[c * 4 + cc]) * inv);
        *(u16x4*)(prow + j0) = pk;
      }
    }
  }
}

// ---------- Y = P @ V^T: 64-row blocks, LPT (big rt first) — R13-validated form ----------
__global__ __launch_bounds__(512) void pv_k(const float* __restrict__ S,
    const unsigned short* __restrict__ Vt,
    unsigned short* __restrict__ Yhi, unsigned short* __restrict__ Ylo, int bh0) {
  __shared__ unsigned short Ps[64][136];
  __shared__ unsigned short Vs[64][136];
  const int x = blockIdx.x;                    // 0..2*NRT-1
  const int rt = NRT - 1 - (x >> 1);           // big rt dispatched first
  const int half = x & 1;
  const int bh = bh0 + blockIdx.y, b = bh >> 3, h = bh & 7;
  const int tid = threadIdx.x, w = tid >> 6, lane = tid & 63, e = lane >> 4, lr = lane & 15;
  const int stride = (rt + 1) * 128;
  const int rbase = half * 64;                 // local row base within the 128-row tile
  const float* Srow0 = S + (size_t)(bh - bh0) * TRI_FLOATS + (size_t)tri_i(rt) * 16384;
  const int rg = w & 3, dh = w >> 2;           // row-group (16 rows), d-half (32 cols)
  f32x4 acc[2] = {};
  for (int kt = 0; kt <= rt; kt++) {
#pragma unroll
    for (int p = 0; p < 2; p++) {
      int idx = tid + p * 512, pr = idx >> 4, seg = idx & 15;
      const unsigned short* src =
          (const unsigned short*)(Srow0 + (size_t)(rbase + pr) * stride) + kt * 128 + seg * 8;
      *(u16x8*)&Ps[pr][seg * 8] = *(const u16x8*)src;
      *(u16x8*)&Vs[pr][seg * 8] = *(const u16x8*)&Vt[((size_t)(bh * 64 + pr)) * Tc + kt * 128 + seg * 8];
    }
    __syncthreads();
#pragma unroll
    for (int ks = 0; ks < 4; ks++) {
      s16x8 a = *(const s16x8*)&Ps[rg * 16 + lr][ks * 32 + e * 8];
#pragma unroll
      for (int tj = 0; tj < 2; tj++) {
        s16x8 bb = *(const s16x8*)&Vs[dh * 32 + tj * 16 + lr][ks * 32 + e * 8];
        acc[tj] = __builtin_amdgcn_mfma_f32_16x16x32_bf16(a, bb, acc[tj], 0, 0, 0);
      }
    }
    __syncthreads();
  }
#pragma unroll
  for (int tj = 0; tj < 2; tj++)
#pragma unroll
    for (int r = 0; r < 4; r++) {
      int row = rt * 128 + rbase + rg * 16 + e * 4 + r;
      size_t g = ((size_t)(b * Tc + row)) * Cch + h * 64 + dh * 32 + tj * 16 + lr;
      float y = acc[tj][r];
      unsigned short hh = f2bf(y);
      Yhi[g] = hh;
      Ylo[g] = f2bf(y - bf2f(hh));
    }
}

extern "C" void kernel_launch(void* const* d_in, const int* in_sizes, int n_in,
                              void* d_out, int out_size, void* d_ws, size_t ws_size,
                              hipStream_t stream) {
  const float* q  = (const float*)d_in[0];
  // d_in[1] = tgt_mask: pure causal tril, handled analytically
  const float* Wq = (const float*)d_in[2];
  const float* bq = (const float*)d_in[3];
  const float* Wk = (const float*)d_in[4];
  const float* bk = (const float*)d_in[5];
  const float* Wv = (const float*)d_in[6];
  const float* bv = (const float*)d_in[7];
  const float* Wp = (const float*)d_in[8];
  const float* bp = (const float*)d_in[9];
  float* out = (float*)d_out;
  char* ws = (char*)d_ws;
  constexpr size_t MB = 1u << 20;

  unsigned short* Yhi = (unsigned short*)(ws + 0 * MB);   // 4 MB
  unsigned short* Ylo = (unsigned short*)(ws + 4 * MB);   // 4 MB
  unsigned short* Qp  = (unsigned short*)(ws + 8 * MB);   // 4 MB
  unsigned short* Kp  = (unsigned short*)(ws + 12 * MB);  // 4 MB
  unsigned short* Vt  = (unsigned short*)(ws + 16 * MB);  // 4 MB
  unsigned short* wsp = (unsigned short*)(ws + 20 * MB);  // 8 x 512 KB weight splits
  float* Sb = (float*)(ws + 24 * MB);                     // S/P region (chunked)

  int nbh = NBH;
  while (nbh > 1 && 24 * MB + TRI_FLOATS * 4 * (size_t)nbh > ws_size) nbh >>= 1;

  splitT4_k<<<dim3(8, 8, 4), 256, 0, stream>>>(Wq, Wk, Wv, Wp, wsp);

  gemm3w_qkv_k<<<dim3(Cch / 64, BT / 128, 3), 512, 0, stream>>>(
      q, wsp, bq, bk, bv, Qp, Kp, Vt);

  for (int c = 0; c < NBH / nbh; c++) {
    int bh0 = c * nbh;
    sqk_k<<<dim3(NTRI, nbh), 512, 0, stream>>>(Qp, Kp, Sb, bh0);
    sel_k<<<nbh * 256, 512, 0, stream>>>(Sb);
    pv_k<<<dim3(2 * NRT, nbh), 512, 0, stream>>>(Sb, Vt, Yhi, Ylo, bh0);
  }

  gemm3w_out_k<<<dim3(Cch / 64, BT / 128), 512, 0, stream>>>(
      Yhi, Ylo, wsp + (size_t)6 * 262144, wsp + (size_t)7 * 262144, bp, out);
}